// Round 2
// baseline (978.136 us; speedup 1.0000x reference)
//
#include <hip/hip_runtime.h>
#include <math.h>

// Problem constants (B=2, T=2048, DIM=1024, H=16, HKV=4, D=64, ROPE_DIMS=32)
namespace {
constexpr int kT    = 2048;
constexpr int kDim  = 1024;
constexpr int kH    = 16;
constexpr int kHKV  = 4;
constexpr int kD    = 64;
constexpr int kTok  = 4096;   // B*T
constexpr int kQKVN = 1536;   // DIM + 2*HKV*D
}

// ---------------- fake-quant: per-row absmax, RNE round, clip ----------------
__global__ __launch_bounds__(256) void quant_kernel(
    const float* __restrict__ w, float* __restrict__ out, int cols, float halfv)
{
  const int row = blockIdx.x;
  const float* src = w + (size_t)row * cols;
  float* dst = out + (size_t)row * cols;
  float mx = 0.0f;
  for (int c = threadIdx.x; c < cols; c += 256)
    mx = fmaxf(mx, fabsf(src[c]));
  #pragma unroll
  for (int m = 1; m < 64; m <<= 1) mx = fmaxf(mx, __shfl_xor(mx, m));
  __shared__ float red[4];
  if ((threadIdx.x & 63) == 0) red[threadIdx.x >> 6] = mx;
  __syncthreads();
  mx = fmaxf(fmaxf(red[0], red[1]), fmaxf(red[2], red[3]));
  const float wmax = fmaxf(mx, 1e-5f);
  const float inv_half = 1.0f / halfv;
  for (int c = threadIdx.x; c < cols; c += 256) {
    float v = src[c];
    float r = rintf(v / wmax * halfv);          // rintf == round-half-even == np.round
    r = fminf(fmaxf(r, -halfv), halfv - 1.0f);
    dst[c] = r * inv_half * wmax;
  }
}

// ---------------- GEMM: C[m][n] = sum_k A[m][k] * W[n][k] --------------------
// A: M x K row-major, W: N x K row-major (weight, so this is A @ W^T), C: ldc stride.
// 64x64 tile, BK=16, 256 threads, 4x4 microtile. LDS stride 68 (16B-aligned pad).
__global__ __launch_bounds__(256) void gemm_wt(
    const float* __restrict__ A, const float* __restrict__ W,
    float* __restrict__ C, int K, int ldc)
{
  __shared__ float As[16][68];  // [k][m]
  __shared__ float Ws[16][68];  // [k][n]
  const int tid = threadIdx.x;
  const int tx = tid & 15, ty = tid >> 4;
  const int m0 = blockIdx.y * 64, n0 = blockIdx.x * 64;
  const int r = tid >> 2, k4 = (tid & 3) * 4;  // 64 rows x 16 cols tile: exact cover
  float acc[4][4] = {};
  for (int k0 = 0; k0 < K; k0 += 16) {
    const float4 av = *(const float4*)(A + (size_t)(m0 + r) * K + k0 + k4);
    const float4 wv = *(const float4*)(W + (size_t)(n0 + r) * K + k0 + k4);
    __syncthreads();
    As[k4+0][r] = av.x; As[k4+1][r] = av.y; As[k4+2][r] = av.z; As[k4+3][r] = av.w;
    Ws[k4+0][r] = wv.x; Ws[k4+1][r] = wv.y; Ws[k4+2][r] = wv.z; Ws[k4+3][r] = wv.w;
    __syncthreads();
    #pragma unroll
    for (int kk = 0; kk < 16; ++kk) {
      const float4 a = *(const float4*)&As[kk][4*ty];
      const float4 b = *(const float4*)&Ws[kk][4*tx];
      const float aa[4] = {a.x, a.y, a.z, a.w};
      const float bb[4] = {b.x, b.y, b.z, b.w};
      #pragma unroll
      for (int i = 0; i < 4; ++i)
        #pragma unroll
        for (int j = 0; j < 4; ++j)
          acc[i][j] = fmaf(aa[i], bb[j], acc[i][j]);
    }
  }
  #pragma unroll
  for (int i = 0; i < 4; ++i) {
    const float4 o = make_float4(acc[i][0], acc[i][1], acc[i][2], acc[i][3]);
    *(float4*)(C + (size_t)(m0 + 4*ty + i) * ldc + n0 + 4*tx) = o;
  }
}

// -------- RMSNorm + RoPE(+gain) + scatter qkv -> per-head layouts ------------
// One wave per head-row. slots: 0..15 q, 16..19 k, 20..23 v(copy only).
__global__ __launch_bounds__(256) void normrope_kernel(
    const float* __restrict__ qkv, const float* __restrict__ q_gain,
    float* __restrict__ qh, float* __restrict__ kh, float* __restrict__ vh)
{
  const int lane = threadIdx.x & 63;
  const int w    = threadIdx.x >> 6;
  const int rid  = blockIdx.x * 4 + w;          // 0 .. B*T*24-1
  const int slot = rid % 24;
  const int tok  = rid / 24;                    // b*T + t
  const int t    = tok & (kT - 1);
  const int b    = tok >> 11;                   // / 2048

  const float* src;
  float* dst;
  if (slot < 16) {
    src = qkv + (size_t)tok * kQKVN + slot * kD;
    dst = qh + ((size_t)(b * kH + slot) * kT + t) * kD;
  } else if (slot < 20) {
    const int kvh = slot - 16;
    src = qkv + (size_t)tok * kQKVN + kDim + kvh * kD;
    dst = kh + ((size_t)(b * kHKV + kvh) * kT + t) * kD;
  } else {
    const int kvh = slot - 20;
    src = qkv + (size_t)tok * kQKVN + kDim + kHKV * kD + kvh * kD;
    dst = vh + ((size_t)(b * kHKV + kvh) * kT + t) * kD;
  }

  const float x = src[lane];
  if (slot < 20) {
    float ss = x * x;
    #pragma unroll
    for (int m = 1; m < 64; m <<= 1) ss += __shfl_xor(ss, m);
    const float xn = x * (1.0f / sqrtf(ss * (1.0f / 64.0f) + 1.1920929e-7f));
    const float other = __shfl_xor(xn, 16);
    float xr = xn;
    if (lane < 32) {
      const int i = lane & 15;
      const float fr = (float)t * powf(10000.0f, -(float)i * (1.0f / 16.0f));
      const float c = cosf(fr), s = sinf(fr);
      xr = xn * c + ((lane < 16) ? other : -other) * s;   // [x1*c+x2*s, -x1*s+x2*c]
    }
    if (slot < 16) xr *= q_gain[slot];
    dst[lane] = xr;
  } else {
    dst[lane] = x;
  }
}

// ---------------- causal GQA flash attention + v-projection removal ----------
// block = 256 thr, one (b, h, 64-query tile). Scores & PV as 64x64 LDS GEMMs.
// P reuses ksT buffer (extra barrier). Epilogue reuses diagonal V tile in LDS.
__global__ __launch_bounds__(256) void attn_kernel(
    const float* __restrict__ qh, const float* __restrict__ kh,
    const float* __restrict__ vh, float* __restrict__ yo)
{
  __shared__ float qsT[64][68];   // [d][m]    (later reused as yb[m][d] stride 68)
  __shared__ float ksT[64][68];   // [d][j]    (later reused as ps[j][m] stride 68)
  __shared__ float vs[64][64];    // [j][d]

  const int tid = threadIdx.x;
  const int tx = tid & 15, ty = tid >> 4;
  const int qt = blockIdx.x;                  // 0..31
  const int h = blockIdx.y, b = blockIdx.z;
  const int kv = h >> 2;
  const int q0 = qt * 64;
  const float* qbase = qh + ((size_t)(b * kH + h) * kT + q0) * kD;
  const float* kbase = kh + ((size_t)(b * kHKV + kv) * kT) * kD;
  const float* vbase = vh + ((size_t)(b * kHKV + kv) * kT) * kD;

  // 64x64 tile staging: 4 threads/row, each covers 16 consecutive floats.
  const int r  = tid >> 2;            // 0..63 (row)
  const int c0 = (tid & 3) * 16;      // 0,16,32,48 (col base)
  #pragma unroll
  for (int cc = 0; cc < 16; cc += 4) {
    const float4 v4 = *(const float4*)(qbase + (size_t)r * kD + c0 + cc);
    qsT[c0+cc+0][r] = v4.x; qsT[c0+cc+1][r] = v4.y;
    qsT[c0+cc+2][r] = v4.z; qsT[c0+cc+3][r] = v4.w;
  }

  float m_r[4], l_r[4], acc[4][4];
  #pragma unroll
  for (int i = 0; i < 4; ++i) {
    m_r[i] = -__builtin_inff(); l_r[i] = 0.0f;
    #pragma unroll
    for (int j = 0; j < 4; ++j) acc[i][j] = 0.0f;
  }

  const int ntiles = qt + 1;
  for (int kt = 0; kt < ntiles; ++kt) {
    __syncthreads();   // prev PV done before K/V overwrite (also covers q load, iter 0)
    #pragma unroll
    for (int cc = 0; cc < 16; cc += 4) {
      const float4 kv4 = *(const float4*)(kbase + (size_t)(kt * 64 + r) * kD + c0 + cc);
      ksT[c0+cc+0][r] = kv4.x; ksT[c0+cc+1][r] = kv4.y;
      ksT[c0+cc+2][r] = kv4.z; ksT[c0+cc+3][r] = kv4.w;
      const float4 vv4 = *(const float4*)(vbase + (size_t)(kt * 64 + r) * kD + c0 + cc);
      *(float4*)&vs[r][c0+cc] = vv4;
    }
    __syncthreads();

    // S = Q K^T for this tile: 4x4 per thread
    float s[4][4] = {};
    #pragma unroll 4
    for (int d = 0; d < 64; ++d) {
      const float4 a = *(const float4*)&qsT[d][4*ty];
      const float4 bq = *(const float4*)&ksT[d][4*tx];
      const float aa[4] = {a.x, a.y, a.z, a.w};
      const float bb[4] = {bq.x, bq.y, bq.z, bq.w};
      #pragma unroll
      for (int i = 0; i < 4; ++i)
        #pragma unroll
        for (int j = 0; j < 4; ++j)
          s[i][j] = fmaf(aa[i], bb[j], s[i][j]);
    }

    // scale + causal mask + row max (over 16 tx lanes)
    float rowmax[4];
    #pragma unroll
    for (int i = 0; i < 4; ++i) {
      rowmax[i] = -__builtin_inff();
      const int qp = q0 + 4*ty + i;
      #pragma unroll
      for (int j = 0; j < 4; ++j) {
        const int jp = kt * 64 + 4*tx + j;
        float sv = s[i][j] * 0.125f;
        if (jp > qp) sv = -__builtin_inff();
        s[i][j] = sv;
        rowmax[i] = fmaxf(rowmax[i], sv);
      }
      #pragma unroll
      for (int m = 1; m < 16; m <<= 1)
        rowmax[i] = fmaxf(rowmax[i], __shfl_xor(rowmax[i], m));
    }

    // online softmax update
    float p[4][4];
    #pragma unroll
    for (int i = 0; i < 4; ++i) {
      const float mn = fmaxf(m_r[i], rowmax[i]);       // finite after tile 0
      const float alpha = expf(m_r[i] - mn);           // exp(-inf)=0 on first tile
      float rowsum = 0.0f;
      #pragma unroll
      for (int j = 0; j < 4; ++j) { p[i][j] = expf(s[i][j] - mn); rowsum += p[i][j]; }
      #pragma unroll
      for (int m = 1; m < 16; m <<= 1) rowsum += __shfl_xor(rowsum, m);
      l_r[i] = l_r[i] * alpha + rowsum;
      m_r[i] = mn;
      #pragma unroll
      for (int j = 0; j < 4; ++j) acc[i][j] *= alpha;
    }

    __syncthreads();   // everyone done reading ksT as K
    #pragma unroll
    for (int i = 0; i < 4; ++i)
      #pragma unroll
      for (int j = 0; j < 4; ++j)
        ksT[4*tx + j][4*ty + i] = p[i][j];             // ps[j][m]
    __syncthreads();

    // O += P V
    #pragma unroll 4
    for (int j = 0; j < 64; ++j) {
      const float4 a = *(const float4*)&ksT[j][4*ty];  // P[m=4ty..][j]
      const float4 bv = *(const float4*)&vs[j][4*tx];  // V[j][d=4tx..]
      const float aa[4] = {a.x, a.y, a.z, a.w};
      const float bb[4] = {bv.x, bv.y, bv.z, bv.w};
      #pragma unroll
      for (int i = 0; i < 4; ++i)
        #pragma unroll
        for (int jj = 0; jj < 4; ++jj)
          acc[i][jj] = fmaf(aa[i], bb[jj], acc[i][jj]);
    }
  }

  // finalize into yb (reuse qsT region, stride 68, [m][d])
  float* yb = (float*)qsT;
  #pragma unroll
  for (int i = 0; i < 4; ++i) {
    const float inv_l = 1.0f / l_r[i];
    #pragma unroll
    for (int jj = 0; jj < 4; ++jj)
      yb[(4*ty + i) * 68 + 4*tx + jj] = acc[i][jj] * inv_l;
  }
  __syncthreads();

  // projection removal: vs still holds the diagonal V tile (rows q0..q0+63)
  const int lane = tid & 63, w = tid >> 6;
  for (int rr = 0; rr < 16; ++rr) {
    const int mrow = rr * 4 + w;
    const float yv = yb[mrow * 68 + lane];
    const float vv = vs[mrow][lane];
    float nn = vv * vv;
    #pragma unroll
    for (int m = 1; m < 64; m <<= 1) nn += __shfl_xor(nn, m);
    const float inv = 1.0f / fmaxf(sqrtf(nn), 1e-12f);
    const float vn = vv * inv;
    float dd = yv * vn;
    #pragma unroll
    for (int m = 1; m < 64; m <<= 1) dd += __shfl_xor(dd, m);
    const float outv = yv - dd * vn;
    yo[((size_t)(b * kT + (q0 + mrow)) * kDim) + h * kD + lane] = outv;
  }
}

// ------------------------------- launch --------------------------------------
extern "C" void kernel_launch(void* const* d_in, const int* in_sizes, int n_in,
                              void* d_out, int out_size, void* d_ws, size_t ws_size,
                              hipStream_t stream) {
  (void)in_sizes; (void)n_in; (void)out_size; (void)ws_size;
  const float* x      = (const float*)d_in[0];
  const float* w_q    = (const float*)d_in[1];
  const float* w_k    = (const float*)d_in[2];
  const float* w_v    = (const float*)d_in[3];
  const float* w_proj = (const float*)d_in[4];
  const float* q_gain = (const float*)d_in[5];

  float* ws = (float*)d_ws;
  float* wqq = ws;                      // 1024*1024
  float* wkq = wqq + 1024 * 1024;       // 256*1024
  float* wvq = wkq + 256 * 1024;        // 256*1024
  float* wpq = wvq + 256 * 1024;        // 1024*1024
  float* qkv = wpq + 1024 * 1024;       // 4096*1536
  float* qh  = qkv + (size_t)kTok * kQKVN;   // B,H,T,D   = 4194304
  float* kh  = qh + (size_t)kTok * kDim;     // B,HKV,T,D = 1048576
  float* vh  = kh + (size_t)kTok * kHKV * kD;
  float* yo  = vh + (size_t)kTok * kHKV * kD; // 4096*1024

  // 1) fake-quant weights (6,6,5,5 bits)
  quant_kernel<<<1024, 256, 0, stream>>>(w_q,    wqq, kDim, 32.0f);
  quant_kernel<<<256,  256, 0, stream>>>(w_k,    wkq, kDim, 32.0f);
  quant_kernel<<<256,  256, 0, stream>>>(w_v,    wvq, kDim, 16.0f);
  quant_kernel<<<1024, 256, 0, stream>>>(w_proj, wpq, kDim, 16.0f);

  // 2) QKV GEMMs into qkv buffer (row stride 1536)
  gemm_wt<<<dim3(16, 64), 256, 0, stream>>>(x, wqq, qkv,         kDim, kQKVN);
  gemm_wt<<<dim3(4,  64), 256, 0, stream>>>(x, wkq, qkv + 1024,  kDim, kQKVN);
  gemm_wt<<<dim3(4,  64), 256, 0, stream>>>(x, wvq, qkv + 1280,  kDim, kQKVN);

  // 3) RMSNorm + RoPE + gain, scatter to per-head layouts
  normrope_kernel<<<kTok * 24 / 4, 256, 0, stream>>>(qkv, q_gain, qh, kh, vh);

  // 4) causal GQA flash attention + projection removal -> yo (B,T,DIM)
  attn_kernel<<<dim3(32, kH, 2), 256, 0, stream>>>(qh, kh, vh, yo);

  // 5) output projection
  gemm_wt<<<dim3(16, 64), 256, 0, stream>>>(yo, wpq, (float*)d_out, kDim, kDim);
}

// Round 3
// 369.271 us; speedup vs baseline: 2.6488x; 2.6488x over previous
//
#include <hip/hip_runtime.h>
#include <math.h>

typedef unsigned short u16;
typedef __attribute__((ext_vector_type(8))) short short8;
typedef __attribute__((ext_vector_type(4))) float float4v;

namespace {
constexpr int kT    = 2048;
constexpr int kDim  = 1024;
constexpr int kH    = 16;
constexpr int kHKV  = 4;
constexpr int kD    = 64;
constexpr int kTok  = 4096;   // B*T
constexpr int kQKVN = 1536;   // DIM + 2*HKV*D
}

__device__ __forceinline__ u16 f2bf(float f) {
  unsigned int u = __builtin_bit_cast(unsigned int, f);
  u = (u + 0x7FFFu + ((u >> 16) & 1u)) >> 16;   // RNE
  return (u16)u;
}
__device__ __forceinline__ float bf2f(u16 v) {
  return __builtin_bit_cast(float, (unsigned int)v << 16);
}

// ---------------- fp32 -> bf16 bulk convert (x) ------------------------------
__global__ __launch_bounds__(256) void cvt_bf16(
    const float* __restrict__ x, u16* __restrict__ o)
{
  const size_t i = ((size_t)blockIdx.x * 256 + threadIdx.x) * 8;
  const float4 a = *(const float4*)(x + i);
  const float4 b = *(const float4*)(x + i + 4);
  short8 r;
  r[0] = (short)f2bf(a.x); r[1] = (short)f2bf(a.y);
  r[2] = (short)f2bf(a.z); r[3] = (short)f2bf(a.w);
  r[4] = (short)f2bf(b.x); r[5] = (short)f2bf(b.y);
  r[6] = (short)f2bf(b.z); r[7] = (short)f2bf(b.w);
  *(short8*)(o + i) = r;
}

// ---------------- fake-quant: per-row absmax, RNE round, clip -> bf16 --------
__global__ __launch_bounds__(256) void quant_kernel(
    const float* __restrict__ w, u16* __restrict__ out, int cols, float halfv)
{
  const int row = blockIdx.x;
  const float* src = w + (size_t)row * cols;
  u16* dst = out + (size_t)row * cols;
  float mx = 0.0f;
  for (int c = threadIdx.x; c < cols; c += 256)
    mx = fmaxf(mx, fabsf(src[c]));
  #pragma unroll
  for (int m = 1; m < 64; m <<= 1) mx = fmaxf(mx, __shfl_xor(mx, m));
  __shared__ float red[4];
  if ((threadIdx.x & 63) == 0) red[threadIdx.x >> 6] = mx;
  __syncthreads();
  mx = fmaxf(fmaxf(red[0], red[1]), fmaxf(red[2], red[3]));
  const float wmax = fmaxf(mx, 1e-5f);
  const float inv_half = 1.0f / halfv;
  for (int c = threadIdx.x; c < cols; c += 256) {
    float v = src[c];
    float r = rintf(v / wmax * halfv);
    r = fminf(fmaxf(r, -halfv), halfv - 1.0f);
    dst[c] = f2bf(r * inv_half * wmax);
  }
}

// ---------------- bf16 MFMA GEMM: C[m][n] = sum_k A[m][k] * W[n][k] ----------
// 64x64 tile, BK=32, 256 thr / 4 waves; wave -> 16-row strip. fp32 C out.
__global__ __launch_bounds__(256) void gemm_bf16(
    const u16* __restrict__ A, const u16* __restrict__ W,
    float* __restrict__ C, int K, int ldc)
{
  __shared__ u16 As[64][40];   // [m][k], pad 40 (5x16B rows -> conflict-free b128)
  __shared__ u16 Ws[64][40];   // [n][k]
  const int tid = threadIdx.x;
  const int lane = tid & 63, wq = tid >> 6;
  const int n = lane & 15, quad = lane >> 4;
  const int m0 = blockIdx.y * 64, n0 = blockIdx.x * 64;
  const int r = tid >> 2, c8 = (tid & 3) * 8;   // staging: 64 rows x 32 cols
  float4v acc[4];
  #pragma unroll
  for (int g = 0; g < 4; ++g) { acc[g][0]=0.f; acc[g][1]=0.f; acc[g][2]=0.f; acc[g][3]=0.f; }

  for (int k0 = 0; k0 < K; k0 += 32) {
    const short8 av = *(const short8*)(A + (size_t)(m0 + r) * K + k0 + c8);
    const short8 wv = *(const short8*)(W + (size_t)(n0 + r) * K + k0 + c8);
    __syncthreads();
    *(short8*)&As[r][c8] = av;
    *(short8*)&Ws[r][c8] = wv;
    __syncthreads();
    const short8 a = *(const short8*)&As[wq * 16 + n][quad * 8];
    #pragma unroll
    for (int g = 0; g < 4; ++g) {
      const short8 b = *(const short8*)&Ws[g * 16 + n][quad * 8];
      acc[g] = __builtin_amdgcn_mfma_f32_16x16x32_bf16(a, b, acc[g], 0, 0, 0);
    }
  }
  #pragma unroll
  for (int g = 0; g < 4; ++g)
    #pragma unroll
    for (int i = 0; i < 4; ++i)
      C[(size_t)(m0 + wq * 16 + quad * 4 + i) * ldc + n0 + g * 16 + n] = acc[g][i];
}

// -------- RMSNorm + RoPE(+gain*0.125) + scatter -> bf16 per-head layouts -----
__global__ __launch_bounds__(256) void normrope_kernel(
    const float* __restrict__ qkv, const float* __restrict__ q_gain,
    u16* __restrict__ qh, u16* __restrict__ kh, u16* __restrict__ vh)
{
  const int lane = threadIdx.x & 63;
  const int w    = threadIdx.x >> 6;
  const int rid  = blockIdx.x * 4 + w;
  const int slot = rid % 24;
  const int tok  = rid / 24;
  const int t    = tok & (kT - 1);
  const int b    = tok >> 11;

  const float* src;
  u16* dst;
  if (slot < 16) {
    src = qkv + (size_t)tok * kQKVN + slot * kD;
    dst = qh + ((size_t)(b * kH + slot) * kT + t) * kD;
  } else if (slot < 20) {
    const int kvh = slot - 16;
    src = qkv + (size_t)tok * kQKVN + kDim + kvh * kD;
    dst = kh + ((size_t)(b * kHKV + kvh) * kT + t) * kD;
  } else {
    const int kvh = slot - 20;
    src = qkv + (size_t)tok * kQKVN + kDim + kHKV * kD + kvh * kD;
    dst = vh + ((size_t)(b * kHKV + kvh) * kT + t) * kD;
  }

  const float x = src[lane];
  if (slot < 20) {
    float ss = x * x;
    #pragma unroll
    for (int m = 1; m < 64; m <<= 1) ss += __shfl_xor(ss, m);
    const float xn = x * (1.0f / sqrtf(ss * (1.0f / 64.0f) + 1.1920929e-7f));
    const float other = __shfl_xor(xn, 16);
    float xr = xn;
    if (lane < 32) {
      const int i = lane & 15;
      const float fr = (float)t * powf(10000.0f, -(float)i * (1.0f / 16.0f));
      const float c = cosf(fr), s = sinf(fr);
      xr = xn * c + ((lane < 16) ? other : -other) * s;
    }
    if (slot < 16) xr *= q_gain[slot] * 0.125f;   // fold 1/sqrt(D) into q
    dst[lane] = f2bf(xr);
  } else {
    dst[lane] = f2bf(x);
  }
}

// ---------------- MFMA causal GQA flash attention + v-projection removal -----
// block = 256 thr / 4 waves; block owns 64 q-rows, wave owns a 16-row strip.
// mfma 16x16x32 bf16; P round-trips per-wave LDS (verified m120 pattern).
__global__ __launch_bounds__(256) void attn_mfma(
    const u16* __restrict__ qh, const u16* __restrict__ kh,
    const u16* __restrict__ vh, const float* __restrict__ qkv,
    u16* __restrict__ yo)
{
  __shared__ u16 ks[64][72];        // K tile [row][d], pad 72
  __shared__ u16 vsT[64][72];       // V tile transposed [d][row]
  __shared__ u16 ps[4][16][72];     // per-wave P strip [row][col]

  const int tid = threadIdx.x;
  const int lane = tid & 63, wq = tid >> 6;
  const int n = lane & 15, quad = lane >> 4;
  const int qt = blockIdx.x, h = blockIdx.y, b = blockIdx.z;
  const int kv = h >> 2;
  const int q0 = qt * 64;
  const u16* qbase = qh + ((size_t)(b * kH + h) * kT + q0) * kD;
  const u16* kbase = kh + ((size_t)(b * kHKV + kv) * kT) * kD;
  const u16* vbase = vh + ((size_t)(b * kHKV + kv) * kT) * kD;

  // Q fragments stay in registers for the whole kernel (A-layout, contiguous d)
  const short8 qa0 = *(const short8*)(qbase + (size_t)(wq * 16 + n) * kD + quad * 8);
  const short8 qa1 = *(const short8*)(qbase + (size_t)(wq * 16 + n) * kD + 32 + quad * 8);

  const int sr = tid >> 3, sc = (tid & 7) * 8;   // staging: 8 thr/row x 16B

  float m_r[4], l_r[4];
  float4v acc[4];
  #pragma unroll
  for (int g = 0; g < 4; ++g) { acc[g][0]=0.f; acc[g][1]=0.f; acc[g][2]=0.f; acc[g][3]=0.f; }
  #pragma unroll
  for (int i = 0; i < 4; ++i) { m_r[i] = -__builtin_inff(); l_r[i] = 0.0f; }

  for (int kt = 0; kt <= qt; ++kt) {
    __syncthreads();   // prev iter's MFMA reads done before overwrite
    #pragma unroll
    for (int rr = 0; rr < 64; rr += 32) {
      const short8 kvv = *(const short8*)(kbase + (size_t)(kt * 64 + sr + rr) * kD + sc);
      *(short8*)&ks[sr + rr][sc] = kvv;
      const short8 vvv = *(const short8*)(vbase + (size_t)(kt * 64 + sr + rr) * kD + sc);
      #pragma unroll
      for (int j = 0; j < 8; ++j) vsT[sc + j][sr + rr] = (u16)vvv[j];
    }
    __syncthreads();

    // S = Q K^T (scores already scaled via q)
    float4v s[4];
    #pragma unroll
    for (int g = 0; g < 4; ++g) { s[g][0]=0.f; s[g][1]=0.f; s[g][2]=0.f; s[g][3]=0.f; }
    #pragma unroll
    for (int g = 0; g < 4; ++g) {
      const short8 b0 = *(const short8*)&ks[g * 16 + n][quad * 8];
      s[g] = __builtin_amdgcn_mfma_f32_16x16x32_bf16(qa0, b0, s[g], 0, 0, 0);
      const short8 b1 = *(const short8*)&ks[g * 16 + n][32 + quad * 8];
      s[g] = __builtin_amdgcn_mfma_f32_16x16x32_bf16(qa1, b1, s[g], 0, 0, 0);
    }

    if (kt == qt) {    // causal mask only on the diagonal tile
      #pragma unroll
      for (int g = 0; g < 4; ++g) {
        const int col = g * 16 + n;
        #pragma unroll
        for (int i = 0; i < 4; ++i)
          if (col > wq * 16 + quad * 4 + i) s[g][i] = -__builtin_inff();
      }
    }

    // online softmax (rows live in 16-lane groups: shfl masks 1..8)
    #pragma unroll
    for (int i = 0; i < 4; ++i) {
      float mx = fmaxf(fmaxf(s[0][i], s[1][i]), fmaxf(s[2][i], s[3][i]));
      #pragma unroll
      for (int m = 1; m < 16; m <<= 1) mx = fmaxf(mx, __shfl_xor(mx, m));
      const float mn = fmaxf(m_r[i], mx);
      const float alpha = __expf(m_r[i] - mn);
      m_r[i] = mn;
      float pv[4]; float rs = 0.0f;
      #pragma unroll
      for (int g = 0; g < 4; ++g) { pv[g] = __expf(s[g][i] - mn); rs += pv[g]; }
      #pragma unroll
      for (int m = 1; m < 16; m <<= 1) rs += __shfl_xor(rs, m);
      l_r[i] = l_r[i] * alpha + rs;
      #pragma unroll
      for (int g = 0; g < 4; ++g) {
        acc[g][i] *= alpha;
        ps[wq][quad * 4 + i][g * 16 + n] = f2bf(pv[g]);   // C-layout -> LDS
      }
    }

    // P back out in A-layout (same wave: no barrier needed, lgkmcnt handles)
    const short8 pa0 = *(const short8*)&ps[wq][n][quad * 8];
    const short8 pa1 = *(const short8*)&ps[wq][n][32 + quad * 8];
    #pragma unroll
    for (int g = 0; g < 4; ++g) {
      const short8 vb0 = *(const short8*)&vsT[g * 16 + n][quad * 8];
      acc[g] = __builtin_amdgcn_mfma_f32_16x16x32_bf16(pa0, vb0, acc[g], 0, 0, 0);
      const short8 vb1 = *(const short8*)&vsT[g * 16 + n][32 + quad * 8];
      acc[g] = __builtin_amdgcn_mfma_f32_16x16x32_bf16(pa1, vb1, acc[g], 0, 0, 0);
    }
  }

  // epilogue: normalize by l, remove projection onto normalized v (fp32 v from qkv)
  #pragma unroll
  for (int i = 0; i < 4; ++i) {
    const int rloc = wq * 16 + quad * 4 + i;
    const int tok = b * kT + q0 + rloc;
    const float invl = 1.0f / l_r[i];
    float vv[4]; float nn = 0.0f, sy = 0.0f;
    #pragma unroll
    for (int g = 0; g < 4; ++g) {
      vv[g] = qkv[(size_t)tok * kQKVN + kDim + kHKV * kD + kv * kD + g * 16 + n];
      nn += vv[g] * vv[g];
      sy += acc[g][i] * invl * vv[g];
    }
    #pragma unroll
    for (int m = 1; m < 16; m <<= 1) { nn += __shfl_xor(nn, m); sy += __shfl_xor(sy, m); }
    const float inv = 1.0f / fmaxf(sqrtf(nn), 1e-12f);
    const float coef = sy * inv * inv;
    #pragma unroll
    for (int g = 0; g < 4; ++g) {
      const float outv = acc[g][i] * invl - coef * vv[g];
      yo[(size_t)tok * kDim + h * kD + g * 16 + n] = f2bf(outv);
    }
  }
}

// ------------------------------- launch --------------------------------------
extern "C" void kernel_launch(void* const* d_in, const int* in_sizes, int n_in,
                              void* d_out, int out_size, void* d_ws, size_t ws_size,
                              hipStream_t stream) {
  (void)in_sizes; (void)n_in; (void)out_size; (void)ws_size;
  const float* x      = (const float*)d_in[0];
  const float* w_q    = (const float*)d_in[1];
  const float* w_k    = (const float*)d_in[2];
  const float* w_v    = (const float*)d_in[3];
  const float* w_proj = (const float*)d_in[4];
  const float* q_gain = (const float*)d_in[5];

  char* wsb = (char*)d_ws;
  u16* wqq = (u16*)wsb;  wsb += (size_t)1024 * 1024 * 2;
  u16* wkq = (u16*)wsb;  wsb += (size_t)256  * 1024 * 2;
  u16* wvq = (u16*)wsb;  wsb += (size_t)256  * 1024 * 2;
  u16* wpq = (u16*)wsb;  wsb += (size_t)1024 * 1024 * 2;
  u16* xb  = (u16*)wsb;  wsb += (size_t)kTok * kDim * 2;
  float* qkv = (float*)wsb; wsb += (size_t)kTok * kQKVN * 4;
  u16* qh  = (u16*)wsb;  wsb += (size_t)kTok * kDim * 2;
  u16* khb = (u16*)wsb;  wsb += (size_t)kTok * kHKV * kD * 2;
  u16* vhb = (u16*)wsb;  wsb += (size_t)kTok * kHKV * kD * 2;
  u16* yo  = (u16*)wsb;  wsb += (size_t)kTok * kDim * 2;

  // 1) x -> bf16
  cvt_bf16<<<kTok * kDim / (8 * 256), 256, 0, stream>>>(x, xb);

  // 2) fake-quant weights -> bf16 (6,6,5,5 bits)
  quant_kernel<<<1024, 256, 0, stream>>>(w_q,    wqq, kDim, 32.0f);
  quant_kernel<<<256,  256, 0, stream>>>(w_k,    wkq, kDim, 32.0f);
  quant_kernel<<<256,  256, 0, stream>>>(w_v,    wvq, kDim, 16.0f);
  quant_kernel<<<1024, 256, 0, stream>>>(w_proj, wpq, kDim, 16.0f);

  // 3) QKV GEMMs (fp32 out, row stride 1536)
  gemm_bf16<<<dim3(16, 64), 256, 0, stream>>>(xb, wqq, qkv,        kDim, kQKVN);
  gemm_bf16<<<dim3(4,  64), 256, 0, stream>>>(xb, wkq, qkv + 1024, kDim, kQKVN);
  gemm_bf16<<<dim3(4,  64), 256, 0, stream>>>(xb, wvq, qkv + 1280, kDim, kQKVN);

  // 4) RMSNorm + RoPE + gain/8 -> bf16 per-head layouts
  normrope_kernel<<<kTok * 24 / 4, 256, 0, stream>>>(qkv, q_gain, qh, khb, vhb);

  // 5) MFMA flash attention + projection removal -> yo (bf16)
  attn_mfma<<<dim3(32, kH, 2), 256, 0, stream>>>(qh, khb, vhb, qkv, yo);

  // 6) output projection (fp32 out)
  gemm_bf16<<<dim3(16, 64), 256, 0, stream>>>(yo, wpq, (float*)d_out, kDim, kDim);
}

// Round 4
// 257.064 us; speedup vs baseline: 3.8050x; 1.4365x over previous
//
#include <hip/hip_runtime.h>
#include <math.h>

typedef unsigned short u16;
typedef __attribute__((ext_vector_type(8))) short short8;
typedef __attribute__((ext_vector_type(4))) float float4v;
typedef __attribute__((ext_vector_type(4))) u16 ushort4v;

namespace {
constexpr int kT    = 2048;
constexpr int kDim  = 1024;
constexpr int kH    = 16;
constexpr int kHKV  = 4;
constexpr int kD    = 64;
constexpr int kTok  = 4096;   // B*T
constexpr int kQKVN = 1536;   // DIM + 2*HKV*D
}

__device__ __forceinline__ u16 f2bf(float f) {
  unsigned int u = __builtin_bit_cast(unsigned int, f);
  u = (u + 0x7FFFu + ((u >> 16) & 1u)) >> 16;   // RNE
  return (u16)u;
}

// ---------------- fp32 -> bf16 bulk convert (x) ------------------------------
__global__ __launch_bounds__(256) void cvt_bf16(
    const float* __restrict__ x, u16* __restrict__ o)
{
  const size_t i = ((size_t)blockIdx.x * 256 + threadIdx.x) * 8;
  const float4 a = *(const float4*)(x + i);
  const float4 b = *(const float4*)(x + i + 4);
  short8 r;
  r[0] = (short)f2bf(a.x); r[1] = (short)f2bf(a.y);
  r[2] = (short)f2bf(a.z); r[3] = (short)f2bf(a.w);
  r[4] = (short)f2bf(b.x); r[5] = (short)f2bf(b.y);
  r[6] = (short)f2bf(b.z); r[7] = (short)f2bf(b.w);
  *(short8*)(o + i) = r;
}

// ---------------- fake-quant: per-row absmax, RNE round, clip -> bf16 --------
__global__ __launch_bounds__(256) void quant_kernel(
    const float* __restrict__ w, u16* __restrict__ out, int cols, float halfv)
{
  const int row = blockIdx.x;
  const float* src = w + (size_t)row * cols;
  u16* dst = out + (size_t)row * cols;
  float mx = 0.0f;
  for (int c = threadIdx.x; c < cols; c += 256)
    mx = fmaxf(mx, fabsf(src[c]));
  #pragma unroll
  for (int m = 1; m < 64; m <<= 1) mx = fmaxf(mx, __shfl_xor(mx, m));
  __shared__ float red[4];
  if ((threadIdx.x & 63) == 0) red[threadIdx.x >> 6] = mx;
  __syncthreads();
  mx = fmaxf(fmaxf(red[0], red[1]), fmaxf(red[2], red[3]));
  const float wmax = fmaxf(mx, 1e-5f);
  const float inv_half = 1.0f / halfv;
  for (int c = threadIdx.x; c < cols; c += 256) {
    float v = src[c];
    float r = rintf(v / wmax * halfv);
    r = fminf(fmaxf(r, -halfv), halfv - 1.0f);
    dst[c] = f2bf(r * inv_half * wmax);
  }
}

// ---------------- 128x128 bf16 MFMA GEMM: C = A * W^T ------------------------
// 256 thr / 4 waves (2x2 of 64x64); BK=32 (one mfma K-step). XOR-swizzled LDS.
// Optional: for C cols >= 1280 (v range) also emit bf16 V^T [b][kv][d][T].
__global__ __launch_bounds__(256) void gemm128(
    const u16* __restrict__ A, const u16* __restrict__ W,
    float* __restrict__ C, int K, int ldc, u16* __restrict__ vTp)
{
  __shared__ u16 As[128][32];
  __shared__ u16 Ws[128][32];
  const int tid = threadIdx.x;
  const int lane = tid & 63, wv = tid >> 6;
  const int n = lane & 15, quad = lane >> 4;
  const int wm = (wv & 1) * 64, wn = (wv >> 1) * 64;
  const int m0 = blockIdx.y * 128, n0 = blockIdx.x * 128;
  const int sr = tid >> 2, sc = (tid & 3) * 8;
  const int scs = sc ^ ((sr & 3) * 8);          // swizzled staging col

  float4v acc[4][4];
  #pragma unroll
  for (int mi = 0; mi < 4; ++mi)
    #pragma unroll
    for (int ni = 0; ni < 4; ++ni) { acc[mi][ni][0]=0.f; acc[mi][ni][1]=0.f; acc[mi][ni][2]=0.f; acc[mi][ni][3]=0.f; }

  for (int k0 = 0; k0 < K; k0 += 32) {
    const short8 a0 = *(const short8*)(A + (size_t)(m0 + sr) * K + k0 + sc);
    const short8 a1 = *(const short8*)(A + (size_t)(m0 + sr + 64) * K + k0 + sc);
    const short8 w0 = *(const short8*)(W + (size_t)(n0 + sr) * K + k0 + sc);
    const short8 w1 = *(const short8*)(W + (size_t)(n0 + sr + 64) * K + k0 + sc);
    __syncthreads();
    *(short8*)&As[sr][scs] = a0;  *(short8*)&As[sr + 64][scs] = a1;
    *(short8*)&Ws[sr][scs] = w0;  *(short8*)&Ws[sr + 64][scs] = w1;
    __syncthreads();
    short8 af[4], bf[4];
    #pragma unroll
    for (int mi = 0; mi < 4; ++mi)
      af[mi] = *(const short8*)&As[wm + mi * 16 + n][(quad * 8) ^ ((n & 3) * 8)];
    #pragma unroll
    for (int ni = 0; ni < 4; ++ni)
      bf[ni] = *(const short8*)&Ws[wn + ni * 16 + n][(quad * 8) ^ ((n & 3) * 8)];
    #pragma unroll
    for (int mi = 0; mi < 4; ++mi)
      #pragma unroll
      for (int ni = 0; ni < 4; ++ni)
        acc[mi][ni] = __builtin_amdgcn_mfma_f32_16x16x32_bf16(af[mi], bf[ni], acc[mi][ni], 0, 0, 0);
  }

  #pragma unroll
  for (int mi = 0; mi < 4; ++mi) {
    const int r0 = m0 + wm + mi * 16 + quad * 4;
    #pragma unroll
    for (int ni = 0; ni < 4; ++ni) {
      const int col = n0 + wn + ni * 16 + n;
      #pragma unroll
      for (int i = 0; i < 4; ++i)
        C[(size_t)(r0 + i) * ldc + col] = acc[mi][ni][i];
      if (vTp != nullptr && col >= 1280) {      // V^T side output (bf16)
        const int vd = col - 1280;              // 0..255
        const int kvh = vd >> 6, d = vd & 63;
        const int bb = r0 >> 11, t0 = r0 & 2047;
        ushort4v pk;
        pk[0] = f2bf(acc[mi][ni][0]); pk[1] = f2bf(acc[mi][ni][1]);
        pk[2] = f2bf(acc[mi][ni][2]); pk[3] = f2bf(acc[mi][ni][3]);
        *(ushort4v*)(vTp + ((size_t)((bb * kHKV + kvh) * kD + d)) * kT + t0) = pk;
      }
    }
  }
}

// -------- RMSNorm + RoPE(+gain*0.125) + scatter -> bf16 q/k layouts ----------
// 20 slots/token: 0..15 q heads, 16..19 k heads (v handled by gemm128's vT).
__global__ __launch_bounds__(256) void normrope_kernel(
    const float* __restrict__ qkv, const float* __restrict__ q_gain,
    u16* __restrict__ qh, u16* __restrict__ kh)
{
  const int lane = threadIdx.x & 63;
  const int w    = threadIdx.x >> 6;
  const int rid  = blockIdx.x * 4 + w;
  const int slot = rid % 20;
  const int tok  = rid / 20;
  const int t    = tok & (kT - 1);
  const int b    = tok >> 11;

  const float* src;
  u16* dst;
  if (slot < 16) {
    src = qkv + (size_t)tok * kQKVN + slot * kD;
    dst = qh + ((size_t)(b * kH + slot) * kT + t) * kD;
  } else {
    const int kvh = slot - 16;
    src = qkv + (size_t)tok * kQKVN + kDim + kvh * kD;
    dst = kh + ((size_t)(b * kHKV + kvh) * kT + t) * kD;
  }

  const float x = src[lane];
  float ss = x * x;
  #pragma unroll
  for (int m = 1; m < 64; m <<= 1) ss += __shfl_xor(ss, m);
  const float xn = x * (1.0f / sqrtf(ss * (1.0f / 64.0f) + 1.1920929e-7f));
  const float other = __shfl_xor(xn, 16);
  float xr = xn;
  if (lane < 32) {
    const int i = lane & 15;
    const float fr = (float)t * powf(10000.0f, -(float)i * (1.0f / 16.0f));
    const float c = cosf(fr), s = sinf(fr);
    xr = xn * c + ((lane < 16) ? other : -other) * s;
  }
  if (slot < 16) xr *= q_gain[slot] * 0.125f;   // fold 1/sqrt(D) into q
  dst[lane] = f2bf(xr);
}

// ---------------- MFMA causal flash attention, paired q-tiles ----------------
// Block = pair p: q-tiles (p, 31-p). Shared K/V staging; double MFMA on the
// common k-prefix. XOR-swizzled LDS (conflict-free b128). Register prefetch.
__global__ __launch_bounds__(256) void attn_mfma(
    const u16* __restrict__ qh, const u16* __restrict__ kh,
    const u16* __restrict__ vT, const float* __restrict__ qkv,
    u16* __restrict__ yo)
{
  __shared__ u16 ks[64][64];     // [token][d], col ^= (token&7)*8
  __shared__ u16 vs[64][64];     // [d][token], col ^= (d&7)*8
  __shared__ u16 ps[4][16][64];  // per-wave P strip, col ^= (row&7)*8

  const int tid = threadIdx.x;
  const int lane = tid & 63, wq = tid >> 6;
  const int n = lane & 15, quad = lane >> 4;
  const int p = blockIdx.x;                     // pair 0..15
  const int h = blockIdx.y, b = blockIdx.z;
  const int kv = h >> 2;
  const int tiles[2] = {p, 31 - p};             // tile A (short), tile B (long)
  const u16* kbase = kh + ((size_t)(b * kHKV + kv) * kT) * kD;
  const u16* vbase = vT + ((size_t)(b * kHKV + kv) * kD) * kT;

  short8 qa[2][2];
  {
    const u16* qb = qh + ((size_t)(b * kH + h) * kT) * kD;
    #pragma unroll
    for (int u = 0; u < 2; ++u) {
      const size_t row = (size_t)(tiles[u] * 64 + wq * 16 + n) * kD;
      qa[u][0] = *(const short8*)(qb + row + quad * 8);
      qa[u][1] = *(const short8*)(qb + row + 32 + quad * 8);
    }
  }

  const int sr = tid >> 3;            // 0..31 (+32 second chunk)
  const int sc = (tid & 7) * 8;
  const int scs = sc ^ ((sr & 7) * 8);   // (sr+32)&7 == sr&7

  float m_r[2][4], l_r[2][4];
  float4v acc[2][4];
  #pragma unroll
  for (int u = 0; u < 2; ++u)
    #pragma unroll
    for (int g = 0; g < 4; ++g) {
      acc[u][g][0]=0.f; acc[u][g][1]=0.f; acc[u][g][2]=0.f; acc[u][g][3]=0.f;
      m_r[u][g] = -__builtin_inff(); l_r[u][g] = 0.0f;
    }

  short8 kr0, kr1, vr0, vr1;
  auto loadKV = [&](int kt) {
    kr0 = *(const short8*)(kbase + (size_t)(kt * 64 + sr) * kD + sc);
    kr1 = *(const short8*)(kbase + (size_t)(kt * 64 + sr + 32) * kD + sc);
    vr0 = *(const short8*)(vbase + (size_t)sr * kT + kt * 64 + sc);
    vr1 = *(const short8*)(vbase + (size_t)(sr + 32) * kT + kt * 64 + sc);
  };

  auto process = [&](int u, int kt) {
    const int tI = tiles[u];
    float4v s[4];
    #pragma unroll
    for (int g = 0; g < 4; ++g) { s[g][0]=0.f; s[g][1]=0.f; s[g][2]=0.f; s[g][3]=0.f; }
    #pragma unroll
    for (int g = 0; g < 4; ++g) {
      const short8 b0 = *(const short8*)&ks[g * 16 + n][(quad * 8) ^ ((n & 7) * 8)];
      s[g] = __builtin_amdgcn_mfma_f32_16x16x32_bf16(qa[u][0], b0, s[g], 0, 0, 0);
      const short8 b1 = *(const short8*)&ks[g * 16 + n][(32 + quad * 8) ^ ((n & 7) * 8)];
      s[g] = __builtin_amdgcn_mfma_f32_16x16x32_bf16(qa[u][1], b1, s[g], 0, 0, 0);
    }
    if (kt == tI) {   // diagonal tile causal mask
      #pragma unroll
      for (int g = 0; g < 4; ++g) {
        const int col = g * 16 + n;
        #pragma unroll
        for (int i = 0; i < 4; ++i)
          if (col > wq * 16 + quad * 4 + i) s[g][i] = -__builtin_inff();
      }
    }
    #pragma unroll
    for (int i = 0; i < 4; ++i) {
      float mx = fmaxf(fmaxf(s[0][i], s[1][i]), fmaxf(s[2][i], s[3][i]));
      #pragma unroll
      for (int m = 1; m < 16; m <<= 1) mx = fmaxf(mx, __shfl_xor(mx, m));
      const float mn = fmaxf(m_r[u][i], mx);
      const float alpha = __expf(m_r[u][i] - mn);
      m_r[u][i] = mn;
      float pv[4]; float rs = 0.0f;
      #pragma unroll
      for (int g = 0; g < 4; ++g) { pv[g] = __expf(s[g][i] - mn); rs += pv[g]; }
      #pragma unroll
      for (int m = 1; m < 16; m <<= 1) rs += __shfl_xor(rs, m);
      l_r[u][i] = l_r[u][i] * alpha + rs;
      const int prow = quad * 4 + i;
      #pragma unroll
      for (int g = 0; g < 4; ++g) {
        acc[u][g][i] *= alpha;
        ps[wq][prow][(g * 16 + n) ^ ((prow & 7) * 8)] = f2bf(pv[g]);
      }
    }
    const short8 pa0 = *(const short8*)&ps[wq][n][(quad * 8) ^ ((n & 7) * 8)];
    const short8 pa1 = *(const short8*)&ps[wq][n][(32 + quad * 8) ^ ((n & 7) * 8)];
    #pragma unroll
    for (int g = 0; g < 4; ++g) {
      const short8 vb0 = *(const short8*)&vs[g * 16 + n][(quad * 8) ^ ((n & 7) * 8)];
      acc[u][g] = __builtin_amdgcn_mfma_f32_16x16x32_bf16(pa0, vb0, acc[u][g], 0, 0, 0);
      const short8 vb1 = *(const short8*)&vs[g * 16 + n][(32 + quad * 8) ^ ((n & 7) * 8)];
      acc[u][g] = __builtin_amdgcn_mfma_f32_16x16x32_bf16(pa1, vb1, acc[u][g], 0, 0, 0);
    }
  };

  const int kmax = tiles[1];
  loadKV(0);
  for (int kt = 0; kt <= kmax; ++kt) {
    __syncthreads();
    *(short8*)&ks[sr][scs]      = kr0;
    *(short8*)&ks[sr + 32][scs] = kr1;
    *(short8*)&vs[sr][scs]      = vr0;
    *(short8*)&vs[sr + 32][scs] = vr1;
    __syncthreads();
    if (kt < kmax) loadKV(kt + 1);
    process(1, kt);                 // long tile, always active
    if (kt <= tiles[0]) process(0, kt);
  }

  // epilogue: normalize by l, remove projection onto normalized v (fp32 qkv)
  #pragma unroll
  for (int u = 0; u < 2; ++u) {
    #pragma unroll
    for (int i = 0; i < 4; ++i) {
      const int rloc = wq * 16 + quad * 4 + i;
      const int tok = b * kT + tiles[u] * 64 + rloc;
      const float invl = 1.0f / l_r[u][i];
      float vv[4]; float nn = 0.0f, sy = 0.0f;
      #pragma unroll
      for (int g = 0; g < 4; ++g) {
        vv[g] = qkv[(size_t)tok * kQKVN + kDim + kHKV * kD + kv * kD + g * 16 + n];
        nn += vv[g] * vv[g];
        sy += acc[u][g][i] * invl * vv[g];
      }
      #pragma unroll
      for (int m = 1; m < 16; m <<= 1) { nn += __shfl_xor(nn, m); sy += __shfl_xor(sy, m); }
      const float inv = 1.0f / fmaxf(sqrtf(nn), 1e-12f);
      const float coef = sy * inv * inv;
      #pragma unroll
      for (int g = 0; g < 4; ++g) {
        const float outv = acc[u][g][i] * invl - coef * vv[g];
        yo[(size_t)tok * kDim + h * kD + g * 16 + n] = f2bf(outv);
      }
    }
  }
}

// ------------------------------- launch --------------------------------------
extern "C" void kernel_launch(void* const* d_in, const int* in_sizes, int n_in,
                              void* d_out, int out_size, void* d_ws, size_t ws_size,
                              hipStream_t stream) {
  (void)in_sizes; (void)n_in; (void)out_size; (void)ws_size;
  const float* x      = (const float*)d_in[0];
  const float* w_q    = (const float*)d_in[1];
  const float* w_k    = (const float*)d_in[2];
  const float* w_v    = (const float*)d_in[3];
  const float* w_proj = (const float*)d_in[4];
  const float* q_gain = (const float*)d_in[5];

  char* wsb = (char*)d_ws;
  u16* wqkv = (u16*)wsb;  wsb += (size_t)1536 * 1024 * 2;   // fused QKV weights
  u16* wpq  = (u16*)wsb;  wsb += (size_t)1024 * 1024 * 2;
  u16* xb   = (u16*)wsb;  wsb += (size_t)kTok * kDim * 2;
  float* qkv = (float*)wsb; wsb += (size_t)kTok * kQKVN * 4;
  u16* qh   = (u16*)wsb;  wsb += (size_t)kTok * kDim * 2;
  u16* khb  = (u16*)wsb;  wsb += (size_t)kTok * kHKV * kD * 2;
  u16* vTb  = (u16*)wsb;  wsb += (size_t)kTok * kHKV * kD * 2;
  u16* yo   = (u16*)wsb;  wsb += (size_t)kTok * kDim * 2;

  // 1) x -> bf16
  cvt_bf16<<<kTok * kDim / (8 * 256), 256, 0, stream>>>(x, xb);

  // 2) fake-quant weights -> bf16 (6,6,5,5 bits) into fused buffer
  quant_kernel<<<1024, 256, 0, stream>>>(w_q,    wqkv,               kDim, 32.0f);
  quant_kernel<<<256,  256, 0, stream>>>(w_k,    wqkv + 1024 * 1024, kDim, 32.0f);
  quant_kernel<<<256,  256, 0, stream>>>(w_v,    wqkv + 1280 * 1024, kDim, 16.0f);
  quant_kernel<<<1024, 256, 0, stream>>>(w_proj, wpq,                kDim, 16.0f);

  // 3) fused QKV GEMM (fp32 out + bf16 V^T side output)
  gemm128<<<dim3(12, 32), 256, 0, stream>>>(xb, wqkv, qkv, kDim, kQKVN, vTb);

  // 4) RMSNorm + RoPE + gain/8 -> bf16 q/k layouts
  normrope_kernel<<<kTok * 20 / 4, 256, 0, stream>>>(qkv, q_gain, qh, khb);

  // 5) paired MFMA flash attention + projection removal -> yo (bf16)
  attn_mfma<<<dim3(16, kH, 2), 256, 0, stream>>>(qh, khb, vTb, qkv, yo);

  // 6) output projection (fp32 out)
  gemm128<<<dim3(8, 32), 256, 0, stream>>>(yo, wpq, (float*)d_out, kDim, kDim, nullptr);
}

// Round 5
// 225.723 us; speedup vs baseline: 4.3333x; 1.1388x over previous
//
#include <hip/hip_runtime.h>
#include <math.h>

typedef unsigned short u16;
typedef __attribute__((ext_vector_type(8))) short short8;
typedef __attribute__((ext_vector_type(4))) float float4v;
typedef __attribute__((ext_vector_type(4))) u16 ushort4v;

namespace {
constexpr int kT    = 2048;
constexpr int kDim  = 1024;
constexpr int kH    = 16;
constexpr int kHKV  = 4;
constexpr int kD    = 64;
constexpr int kTok  = 4096;   // B*T
constexpr int kQKVN = 1536;   // DIM + 2*HKV*D
}

__device__ __forceinline__ u16 f2bf(float f) {
  unsigned int u = __builtin_bit_cast(unsigned int, f);
  u = (u + 0x7FFFu + ((u >> 16) & 1u)) >> 16;   // RNE
  return (u16)u;
}

// ---------------- fp32 -> bf16 bulk convert (x) ------------------------------
__global__ __launch_bounds__(256) void cvt_bf16(
    const float* __restrict__ x, u16* __restrict__ o)
{
  const size_t i = ((size_t)blockIdx.x * 256 + threadIdx.x) * 8;
  const float4 a = *(const float4*)(x + i);
  const float4 b = *(const float4*)(x + i + 4);
  short8 r;
  r[0] = (short)f2bf(a.x); r[1] = (short)f2bf(a.y);
  r[2] = (short)f2bf(a.z); r[3] = (short)f2bf(a.w);
  r[4] = (short)f2bf(b.x); r[5] = (short)f2bf(b.y);
  r[6] = (short)f2bf(b.z); r[7] = (short)f2bf(b.w);
  *(short8*)(o + i) = r;
}

// ---------------- fake-quant: per-row absmax, RNE round, clip -> bf16 --------
__global__ __launch_bounds__(256) void quant_kernel(
    const float* __restrict__ w, u16* __restrict__ out, int cols, float halfv)
{
  const int row = blockIdx.x;
  const float* src = w + (size_t)row * cols;
  u16* dst = out + (size_t)row * cols;
  float mx = 0.0f;
  for (int c = threadIdx.x; c < cols; c += 256)
    mx = fmaxf(mx, fabsf(src[c]));
  #pragma unroll
  for (int m = 1; m < 64; m <<= 1) mx = fmaxf(mx, __shfl_xor(mx, m));
  __shared__ float red[4];
  if ((threadIdx.x & 63) == 0) red[threadIdx.x >> 6] = mx;
  __syncthreads();
  mx = fmaxf(fmaxf(red[0], red[1]), fmaxf(red[2], red[3]));
  const float wmax = fmaxf(mx, 1e-5f);
  const float inv_half = 1.0f / halfv;
  for (int c = threadIdx.x; c < cols; c += 256) {
    float v = src[c];
    float r = rintf(v / wmax * halfv);
    r = fminf(fmaxf(r, -halfv), halfv - 1.0f);
    dst[c] = f2bf(r * inv_half * wmax);
  }
}

// ---------------- rope table: cos/sin per (t, i) -----------------------------
// Bitwise-identical transcendental path to the previously-passing kernel.
__global__ __launch_bounds__(256) void rope_table(float2* __restrict__ tab)
{
  const int idx = blockIdx.x * 256 + threadIdx.x;   // 0..32767
  const int t = idx >> 4, i = idx & 15;
  const float fr = (float)t * powf(10000.0f, -(float)i * (1.0f / 16.0f));
  tab[idx] = make_float2(cosf(fr), sinf(fr));
}

// ---------------- 128x128 bf16 MFMA GEMM: C = A * W^T ------------------------
// 256 thr / 4 waves (2x2 of 64x64); BK=32 (one mfma K-step). XOR-swizzled LDS.
// Optional: for C cols >= 1280 (v range) also emit bf16 V^T [b][kv][d][T].
__global__ __launch_bounds__(256) void gemm128(
    const u16* __restrict__ A, const u16* __restrict__ W,
    float* __restrict__ C, int K, int ldc, u16* __restrict__ vTp)
{
  __shared__ u16 As[128][32];
  __shared__ u16 Ws[128][32];
  const int tid = threadIdx.x;
  const int lane = tid & 63, wv = tid >> 6;
  const int n = lane & 15, quad = lane >> 4;
  const int wm = (wv & 1) * 64, wn = (wv >> 1) * 64;
  const int m0 = blockIdx.y * 128, n0 = blockIdx.x * 128;
  const int sr = tid >> 2, sc = (tid & 3) * 8;
  const int scs = sc ^ ((sr & 3) * 8);          // swizzled staging col

  float4v acc[4][4];
  #pragma unroll
  for (int mi = 0; mi < 4; ++mi)
    #pragma unroll
    for (int ni = 0; ni < 4; ++ni) { acc[mi][ni][0]=0.f; acc[mi][ni][1]=0.f; acc[mi][ni][2]=0.f; acc[mi][ni][3]=0.f; }

  for (int k0 = 0; k0 < K; k0 += 32) {
    const short8 a0 = *(const short8*)(A + (size_t)(m0 + sr) * K + k0 + sc);
    const short8 a1 = *(const short8*)(A + (size_t)(m0 + sr + 64) * K + k0 + sc);
    const short8 w0 = *(const short8*)(W + (size_t)(n0 + sr) * K + k0 + sc);
    const short8 w1 = *(const short8*)(W + (size_t)(n0 + sr + 64) * K + k0 + sc);
    __syncthreads();
    *(short8*)&As[sr][scs] = a0;  *(short8*)&As[sr + 64][scs] = a1;
    *(short8*)&Ws[sr][scs] = w0;  *(short8*)&Ws[sr + 64][scs] = w1;
    __syncthreads();
    short8 af[4], bf[4];
    #pragma unroll
    for (int mi = 0; mi < 4; ++mi)
      af[mi] = *(const short8*)&As[wm + mi * 16 + n][(quad * 8) ^ ((n & 3) * 8)];
    #pragma unroll
    for (int ni = 0; ni < 4; ++ni)
      bf[ni] = *(const short8*)&Ws[wn + ni * 16 + n][(quad * 8) ^ ((n & 3) * 8)];
    #pragma unroll
    for (int mi = 0; mi < 4; ++mi)
      #pragma unroll
      for (int ni = 0; ni < 4; ++ni)
        acc[mi][ni] = __builtin_amdgcn_mfma_f32_16x16x32_bf16(af[mi], bf[ni], acc[mi][ni], 0, 0, 0);
  }

  #pragma unroll
  for (int mi = 0; mi < 4; ++mi) {
    const int r0 = m0 + wm + mi * 16 + quad * 4;
    #pragma unroll
    for (int ni = 0; ni < 4; ++ni) {
      const int col = n0 + wn + ni * 16 + n;
      #pragma unroll
      for (int i = 0; i < 4; ++i)
        C[(size_t)(r0 + i) * ldc + col] = acc[mi][ni][i];
      if (vTp != nullptr && col >= 1280) {      // V^T side output (bf16)
        const int vd = col - 1280;              // 0..255
        const int kvh = vd >> 6, d = vd & 63;
        const int bb = r0 >> 11, t0 = r0 & 2047;
        ushort4v pk;
        pk[0] = f2bf(acc[mi][ni][0]); pk[1] = f2bf(acc[mi][ni][1]);
        pk[2] = f2bf(acc[mi][ni][2]); pk[3] = f2bf(acc[mi][ni][3]);
        *(ushort4v*)(vTp + ((size_t)((bb * kHKV + kvh) * kD + d)) * kT + t0) = pk;
      }
    }
  }
}

// -------- RMSNorm + RoPE(+gain*0.125) + scatter -> bf16 q/k layouts ----------
// 20 slots/token: 0..15 q heads, 16..19 k heads (v handled by gemm128's vT).
__global__ __launch_bounds__(256) void normrope_kernel(
    const float* __restrict__ qkv, const float* __restrict__ q_gain,
    const float2* __restrict__ ropetab,
    u16* __restrict__ qh, u16* __restrict__ kh)
{
  const int lane = threadIdx.x & 63;
  const int w    = threadIdx.x >> 6;
  const int rid  = blockIdx.x * 4 + w;
  const int slot = rid % 20;
  const int tok  = rid / 20;
  const int t    = tok & (kT - 1);
  const int b    = tok >> 11;

  const float* src;
  u16* dst;
  if (slot < 16) {
    src = qkv + (size_t)tok * kQKVN + slot * kD;
    dst = qh + ((size_t)(b * kH + slot) * kT + t) * kD;
  } else {
    const int kvh = slot - 16;
    src = qkv + (size_t)tok * kQKVN + kDim + kvh * kD;
    dst = kh + ((size_t)(b * kHKV + kvh) * kT + t) * kD;
  }

  const float x = src[lane];
  float ss = x * x;
  #pragma unroll
  for (int m = 1; m < 64; m <<= 1) ss += __shfl_xor(ss, m);
  const float xn = x * (1.0f / sqrtf(ss * (1.0f / 64.0f) + 1.1920929e-7f));
  const float other = __shfl_xor(xn, 16);
  float xr = xn;
  if (lane < 32) {
    const float2 cs = ropetab[t * 16 + (lane & 15)];
    xr = xn * cs.x + ((lane < 16) ? other : -other) * cs.y;
  }
  if (slot < 16) xr *= q_gain[slot] * 0.125f;   // fold 1/sqrt(D) into q
  dst[lane] = f2bf(xr);
}

// ---------------- MFMA causal flash attention, paired q-tiles ----------------
// Static-max softmax: scores provably bounded by |q'|*|k| <= 1.5*8 = 12, so
// p = exp(s - 12) needs no running max / rescale. Block = pair (p, 31-p).
__global__ __launch_bounds__(256) void attn_mfma(
    const u16* __restrict__ qh, const u16* __restrict__ kh,
    const u16* __restrict__ vT, const float* __restrict__ qkv,
    u16* __restrict__ yo)
{
  __shared__ u16 ks[64][64];     // [token][d], col ^= (token&7)*8
  __shared__ u16 vs[64][64];     // [d][token], col ^= (d&7)*8
  __shared__ u16 ps[4][16][64];  // per-wave P strip, col ^= (row&7)*8

  const int tid = threadIdx.x;
  const int lane = tid & 63, wq = tid >> 6;
  const int n = lane & 15, quad = lane >> 4;
  const int p = blockIdx.x;                     // pair 0..15
  const int h = blockIdx.y, b = blockIdx.z;
  const int kv = h >> 2;
  const int tiles[2] = {p, 31 - p};             // tile A (short), tile B (long)
  const u16* kbase = kh + ((size_t)(b * kHKV + kv) * kT) * kD;
  const u16* vbase = vT + ((size_t)(b * kHKV + kv) * kD) * kT;

  short8 qa[2][2];
  {
    const u16* qb = qh + ((size_t)(b * kH + h) * kT) * kD;
    #pragma unroll
    for (int u = 0; u < 2; ++u) {
      const size_t row = (size_t)(tiles[u] * 64 + wq * 16 + n) * kD;
      qa[u][0] = *(const short8*)(qb + row + quad * 8);
      qa[u][1] = *(const short8*)(qb + row + 32 + quad * 8);
    }
  }

  const int sr = tid >> 3;            // 0..31 (+32 second chunk)
  const int sc = (tid & 7) * 8;
  const int scs = sc ^ ((sr & 7) * 8);   // (sr+32)&7 == sr&7

  float l_r[2][4];
  float4v acc[2][4];
  #pragma unroll
  for (int u = 0; u < 2; ++u)
    #pragma unroll
    for (int g = 0; g < 4; ++g) {
      acc[u][g][0]=0.f; acc[u][g][1]=0.f; acc[u][g][2]=0.f; acc[u][g][3]=0.f;
      l_r[u][g] = 0.0f;
    }

  short8 kr0, kr1, vr0, vr1;
  auto loadKV = [&](int kt) {
    kr0 = *(const short8*)(kbase + (size_t)(kt * 64 + sr) * kD + sc);
    kr1 = *(const short8*)(kbase + (size_t)(kt * 64 + sr + 32) * kD + sc);
    vr0 = *(const short8*)(vbase + (size_t)sr * kT + kt * 64 + sc);
    vr1 = *(const short8*)(vbase + (size_t)(sr + 32) * kT + kt * 64 + sc);
  };

  auto process = [&](int u, int kt) {
    const int tI = tiles[u];
    float4v s[4];
    #pragma unroll
    for (int g = 0; g < 4; ++g) { s[g][0]=0.f; s[g][1]=0.f; s[g][2]=0.f; s[g][3]=0.f; }
    #pragma unroll
    for (int g = 0; g < 4; ++g) {
      const short8 b0 = *(const short8*)&ks[g * 16 + n][(quad * 8) ^ ((n & 7) * 8)];
      s[g] = __builtin_amdgcn_mfma_f32_16x16x32_bf16(qa[u][0], b0, s[g], 0, 0, 0);
      const short8 b1 = *(const short8*)&ks[g * 16 + n][(32 + quad * 8) ^ ((n & 7) * 8)];
      s[g] = __builtin_amdgcn_mfma_f32_16x16x32_bf16(qa[u][1], b1, s[g], 0, 0, 0);
    }
    if (kt == tI) {   // diagonal tile causal mask
      #pragma unroll
      for (int g = 0; g < 4; ++g) {
        const int col = g * 16 + n;
        #pragma unroll
        for (int i = 0; i < 4; ++i)
          if (col > wq * 16 + quad * 4 + i) s[g][i] = -__builtin_inff();
      }
    }
    #pragma unroll
    for (int i = 0; i < 4; ++i) {
      float pv[4]; float rs = 0.0f;
      #pragma unroll
      for (int g = 0; g < 4; ++g) { pv[g] = __expf(s[g][i] - 12.0f); rs += pv[g]; }
      #pragma unroll
      for (int m = 1; m < 16; m <<= 1) rs += __shfl_xor(rs, m);
      l_r[u][i] += rs;
      const int prow = quad * 4 + i;
      #pragma unroll
      for (int g = 0; g < 4; ++g)
        ps[wq][prow][(g * 16 + n) ^ ((prow & 7) * 8)] = f2bf(pv[g]);
    }
    const short8 pa0 = *(const short8*)&ps[wq][n][(quad * 8) ^ ((n & 7) * 8)];
    const short8 pa1 = *(const short8*)&ps[wq][n][(32 + quad * 8) ^ ((n & 7) * 8)];
    #pragma unroll
    for (int g = 0; g < 4; ++g) {
      const short8 vb0 = *(const short8*)&vs[g * 16 + n][(quad * 8) ^ ((n & 7) * 8)];
      acc[u][g] = __builtin_amdgcn_mfma_f32_16x16x32_bf16(pa0, vb0, acc[u][g], 0, 0, 0);
      const short8 vb1 = *(const short8*)&vs[g * 16 + n][(32 + quad * 8) ^ ((n & 7) * 8)];
      acc[u][g] = __builtin_amdgcn_mfma_f32_16x16x32_bf16(pa1, vb1, acc[u][g], 0, 0, 0);
    }
  };

  const int kmax = tiles[1];
  loadKV(0);
  for (int kt = 0; kt <= kmax; ++kt) {
    __syncthreads();
    *(short8*)&ks[sr][scs]      = kr0;
    *(short8*)&ks[sr + 32][scs] = kr1;
    *(short8*)&vs[sr][scs]      = vr0;
    *(short8*)&vs[sr + 32][scs] = vr1;
    __syncthreads();
    if (kt < kmax) loadKV(kt + 1);
    process(1, kt);                 // long tile, always active
    if (kt <= tiles[0]) process(0, kt);
  }

  // epilogue: normalize by l, remove projection onto normalized v (fp32 qkv)
  #pragma unroll
  for (int u = 0; u < 2; ++u) {
    #pragma unroll
    for (int i = 0; i < 4; ++i) {
      const int rloc = wq * 16 + quad * 4 + i;
      const int tok = b * kT + tiles[u] * 64 + rloc;
      const float invl = 1.0f / l_r[u][i];
      float vv[4]; float nn = 0.0f, sy = 0.0f;
      #pragma unroll
      for (int g = 0; g < 4; ++g) {
        vv[g] = qkv[(size_t)tok * kQKVN + kDim + kHKV * kD + kv * kD + g * 16 + n];
        nn += vv[g] * vv[g];
        sy += acc[u][g][i] * invl * vv[g];
      }
      #pragma unroll
      for (int m = 1; m < 16; m <<= 1) { nn += __shfl_xor(nn, m); sy += __shfl_xor(sy, m); }
      const float inv = 1.0f / fmaxf(sqrtf(nn), 1e-12f);
      const float coef = sy * inv * inv;
      #pragma unroll
      for (int g = 0; g < 4; ++g) {
        const float outv = acc[u][g][i] * invl - coef * vv[g];
        yo[(size_t)tok * kDim + h * kD + g * 16 + n] = f2bf(outv);
      }
    }
  }
}

// ------------------------------- launch --------------------------------------
extern "C" void kernel_launch(void* const* d_in, const int* in_sizes, int n_in,
                              void* d_out, int out_size, void* d_ws, size_t ws_size,
                              hipStream_t stream) {
  (void)in_sizes; (void)n_in; (void)out_size; (void)ws_size;
  const float* x      = (const float*)d_in[0];
  const float* w_q    = (const float*)d_in[1];
  const float* w_k    = (const float*)d_in[2];
  const float* w_v    = (const float*)d_in[3];
  const float* w_proj = (const float*)d_in[4];
  const float* q_gain = (const float*)d_in[5];

  char* wsb = (char*)d_ws;
  u16* wqkv = (u16*)wsb;  wsb += (size_t)1536 * 1024 * 2;   // fused QKV weights
  u16* wpq  = (u16*)wsb;  wsb += (size_t)1024 * 1024 * 2;
  u16* xb   = (u16*)wsb;  wsb += (size_t)kTok * kDim * 2;
  float* qkv = (float*)wsb; wsb += (size_t)kTok * kQKVN * 4;
  u16* qh   = (u16*)wsb;  wsb += (size_t)kTok * kDim * 2;
  u16* khb  = (u16*)wsb;  wsb += (size_t)kTok * kHKV * kD * 2;
  u16* vTb  = (u16*)wsb;  wsb += (size_t)kTok * kHKV * kD * 2;
  u16* yo   = (u16*)wsb;  wsb += (size_t)kTok * kDim * 2;
  float2* ropetab = (float2*)wsb; wsb += (size_t)kT * 16 * sizeof(float2);

  // 0) rope table (cheap, hides behind nothing: 128 blocks)
  rope_table<<<128, 256, 0, stream>>>(ropetab);

  // 1) x -> bf16
  cvt_bf16<<<kTok * kDim / (8 * 256), 256, 0, stream>>>(x, xb);

  // 2) fake-quant weights -> bf16 (6,6,5,5 bits) into fused buffer
  quant_kernel<<<1024, 256, 0, stream>>>(w_q,    wqkv,               kDim, 32.0f);
  quant_kernel<<<256,  256, 0, stream>>>(w_k,    wqkv + 1024 * 1024, kDim, 32.0f);
  quant_kernel<<<256,  256, 0, stream>>>(w_v,    wqkv + 1280 * 1024, kDim, 16.0f);
  quant_kernel<<<1024, 256, 0, stream>>>(w_proj, wpq,                kDim, 16.0f);

  // 3) fused QKV GEMM (fp32 out + bf16 V^T side output)
  gemm128<<<dim3(12, 32), 256, 0, stream>>>(xb, wqkv, qkv, kDim, kQKVN, vTb);

  // 4) RMSNorm + RoPE + gain/8 -> bf16 q/k layouts (table-driven)
  normrope_kernel<<<kTok * 20 / 4, 256, 0, stream>>>(qkv, q_gain, ropetab, qh, khb);

  // 5) paired MFMA flash attention + projection removal -> yo (bf16)
  attn_mfma<<<dim3(16, kH, 2), 256, 0, stream>>>(qh, khb, vTb, qkv, yo);

  // 6) output projection (fp32 out)
  gemm128<<<dim3(8, 32), 256, 0, stream>>>(yo, wpq, (float*)d_out, kDim, kDim, nullptr);
}

// Round 6
// 198.152 us; speedup vs baseline: 4.9363x; 1.1391x over previous
//
#include <hip/hip_runtime.h>
#include <math.h>

typedef unsigned short u16;
typedef __attribute__((ext_vector_type(8))) short short8;
typedef __attribute__((ext_vector_type(4))) float float4v;
typedef __attribute__((ext_vector_type(4))) u16 ushort4v;

namespace {
constexpr int kT    = 2048;
constexpr int kDim  = 1024;
constexpr int kH    = 16;
constexpr int kHKV  = 4;
constexpr int kD    = 64;
constexpr int kTok  = 4096;   // B*T
constexpr int kQKVN = 1536;   // DIM + 2*HKV*D
}

__device__ __forceinline__ u16 f2bf(float f) {
  unsigned int u = __builtin_bit_cast(unsigned int, f);
  u = (u + 0x7FFFu + ((u >> 16) & 1u)) >> 16;   // RNE
  return (u16)u;
}

// ---------------- fused prep: rope table + x->bf16 + 4x fake-quant -----------
// blocks [0,128): rope table; [128,2176): cvt x; [2176,4736): quant rows.
__global__ __launch_bounds__(256) void prep_kernel(
    const float* __restrict__ x,
    const float* __restrict__ w_q, const float* __restrict__ w_k,
    const float* __restrict__ w_v, const float* __restrict__ w_proj,
    u16* __restrict__ xb, u16* __restrict__ wqkv, u16* __restrict__ wpq,
    float2* __restrict__ ropetab)
{
  __shared__ float red[4];
  const int bid = blockIdx.x, tid = threadIdx.x;

  if (bid < 128) {                       // rope table (bitwise-same transcendentals)
    const int idx = bid * 256 + tid;     // 0..32767
    const int t = idx >> 4, i = idx & 15;
    const float fr = (float)t * powf(10000.0f, -(float)i * (1.0f / 16.0f));
    ropetab[idx] = make_float2(cosf(fr), sinf(fr));
    return;
  }
  if (bid < 2176) {                      // x -> bf16, 8 elems/thread
    const size_t i = ((size_t)(bid - 128) * 256 + tid) * 8;
    const float4 a = *(const float4*)(x + i);
    const float4 b = *(const float4*)(x + i + 4);
    short8 r;
    r[0] = (short)f2bf(a.x); r[1] = (short)f2bf(a.y);
    r[2] = (short)f2bf(a.z); r[3] = (short)f2bf(a.w);
    r[4] = (short)f2bf(b.x); r[5] = (short)f2bf(b.y);
    r[6] = (short)f2bf(b.z); r[7] = (short)f2bf(b.w);
    *(short8*)(xb + i) = r;
    return;
  }
  // fake-quant: one block per weight row (1024 cols, 4/thread, register-held)
  const int rid = bid - 2176;            // 0..2559
  const float* src; u16* dst; float halfv;
  if (rid < 1024)      { src = w_q    + (size_t)rid * 1024;          dst = wqkv + (size_t)rid * 1024;          halfv = 32.0f; }
  else if (rid < 1280) { src = w_k    + (size_t)(rid - 1024) * 1024; dst = wqkv + (size_t)rid * 1024;          halfv = 32.0f; }
  else if (rid < 1536) { src = w_v    + (size_t)(rid - 1280) * 1024; dst = wqkv + (size_t)rid * 1024;          halfv = 16.0f; }
  else                 { src = w_proj + (size_t)(rid - 1536) * 1024; dst = wpq  + (size_t)(rid - 1536) * 1024; halfv = 16.0f; }

  const float4 v4 = *(const float4*)(src + tid * 4);
  float mx = fmaxf(fmaxf(fabsf(v4.x), fabsf(v4.y)), fmaxf(fabsf(v4.z), fabsf(v4.w)));
  #pragma unroll
  for (int m = 1; m < 64; m <<= 1) mx = fmaxf(mx, __shfl_xor(mx, m));
  if ((tid & 63) == 0) red[tid >> 6] = mx;
  __syncthreads();
  mx = fmaxf(fmaxf(red[0], red[1]), fmaxf(red[2], red[3]));
  const float wmax = fmaxf(mx, 1e-5f);
  const float inv_half = 1.0f / halfv;
  const float vals[4] = {v4.x, v4.y, v4.z, v4.w};
  ushort4v o;
  #pragma unroll
  for (int j = 0; j < 4; ++j) {
    float r = rintf(vals[j] / wmax * halfv);
    r = fminf(fmaxf(r, -halfv), halfv - 1.0f);
    o[j] = f2bf(r * inv_half * wmax);
  }
  *(ushort4v*)(dst + tid * 4) = o;
}

// ---------------- 128x128 bf16 MFMA GEMM: C = A * W^T ------------------------
// 256 thr / 4 waves (2x2 of 64x64); BK=32. XOR-swizzled LDS (0 conflicts).
// Optional: for C cols >= 1280 (v range) also emit bf16 V^T [b][kv][d][T].
__global__ __launch_bounds__(256) void gemm128(
    const u16* __restrict__ A, const u16* __restrict__ W,
    float* __restrict__ C, int K, int ldc, u16* __restrict__ vTp)
{
  __shared__ u16 As[128][32];
  __shared__ u16 Ws[128][32];
  const int tid = threadIdx.x;
  const int lane = tid & 63, wv = tid >> 6;
  const int n = lane & 15, quad = lane >> 4;
  const int wm = (wv & 1) * 64, wn = (wv >> 1) * 64;
  const int m0 = blockIdx.y * 128, n0 = blockIdx.x * 128;
  const int sr = tid >> 2, sc = (tid & 3) * 8;
  const int scs = sc ^ ((sr & 3) * 8);          // swizzled staging col

  float4v acc[4][4];
  #pragma unroll
  for (int mi = 0; mi < 4; ++mi)
    #pragma unroll
    for (int ni = 0; ni < 4; ++ni) { acc[mi][ni][0]=0.f; acc[mi][ni][1]=0.f; acc[mi][ni][2]=0.f; acc[mi][ni][3]=0.f; }

  for (int k0 = 0; k0 < K; k0 += 32) {
    const short8 a0 = *(const short8*)(A + (size_t)(m0 + sr) * K + k0 + sc);
    const short8 a1 = *(const short8*)(A + (size_t)(m0 + sr + 64) * K + k0 + sc);
    const short8 w0 = *(const short8*)(W + (size_t)(n0 + sr) * K + k0 + sc);
    const short8 w1 = *(const short8*)(W + (size_t)(n0 + sr + 64) * K + k0 + sc);
    __syncthreads();
    *(short8*)&As[sr][scs] = a0;  *(short8*)&As[sr + 64][scs] = a1;
    *(short8*)&Ws[sr][scs] = w0;  *(short8*)&Ws[sr + 64][scs] = w1;
    __syncthreads();
    short8 af[4], bf[4];
    #pragma unroll
    for (int mi = 0; mi < 4; ++mi)
      af[mi] = *(const short8*)&As[wm + mi * 16 + n][(quad * 8) ^ ((n & 3) * 8)];
    #pragma unroll
    for (int ni = 0; ni < 4; ++ni)
      bf[ni] = *(const short8*)&Ws[wn + ni * 16 + n][(quad * 8) ^ ((n & 3) * 8)];
    #pragma unroll
    for (int mi = 0; mi < 4; ++mi)
      #pragma unroll
      for (int ni = 0; ni < 4; ++ni)
        acc[mi][ni] = __builtin_amdgcn_mfma_f32_16x16x32_bf16(af[mi], bf[ni], acc[mi][ni], 0, 0, 0);
  }

  #pragma unroll
  for (int mi = 0; mi < 4; ++mi) {
    const int r0 = m0 + wm + mi * 16 + quad * 4;
    #pragma unroll
    for (int ni = 0; ni < 4; ++ni) {
      const int col = n0 + wn + ni * 16 + n;
      #pragma unroll
      for (int i = 0; i < 4; ++i)
        C[(size_t)(r0 + i) * ldc + col] = acc[mi][ni][i];
      if (vTp != nullptr && col >= 1280) {      // V^T side output (bf16)
        const int vd = col - 1280;              // 0..255
        const int kvh = vd >> 6, d = vd & 63;
        const int bb = r0 >> 11, t0 = r0 & 2047;
        ushort4v pk;
        pk[0] = f2bf(acc[mi][ni][0]); pk[1] = f2bf(acc[mi][ni][1]);
        pk[2] = f2bf(acc[mi][ni][2]); pk[3] = f2bf(acc[mi][ni][3]);
        *(ushort4v*)(vTp + ((size_t)((bb * kHKV + kvh) * kD + d)) * kT + t0) = pk;
      }
    }
  }
}

// -------- RMSNorm + RoPE(+gain*0.125) + scatter -> bf16 q/k layouts ----------
__global__ __launch_bounds__(256) void normrope_kernel(
    const float* __restrict__ qkv, const float* __restrict__ q_gain,
    const float2* __restrict__ ropetab,
    u16* __restrict__ qh, u16* __restrict__ kh)
{
  const int lane = threadIdx.x & 63;
  const int w    = threadIdx.x >> 6;
  const int rid  = blockIdx.x * 4 + w;
  const int slot = rid % 20;
  const int tok  = rid / 20;
  const int t    = tok & (kT - 1);
  const int b    = tok >> 11;

  const float* src;
  u16* dst;
  if (slot < 16) {
    src = qkv + (size_t)tok * kQKVN + slot * kD;
    dst = qh + ((size_t)(b * kH + slot) * kT + t) * kD;
  } else {
    const int kvh = slot - 16;
    src = qkv + (size_t)tok * kQKVN + kDim + kvh * kD;
    dst = kh + ((size_t)(b * kHKV + kvh) * kT + t) * kD;
  }

  const float x = src[lane];
  float ss = x * x;
  #pragma unroll
  for (int m = 1; m < 64; m <<= 1) ss += __shfl_xor(ss, m);
  const float xn = x * (1.0f / sqrtf(ss * (1.0f / 64.0f) + 1.1920929e-7f));
  const float other = __shfl_xor(xn, 16);
  float xr = xn;
  if (lane < 32) {
    const float2 cs = ropetab[t * 16 + (lane & 15)];
    xr = xn * cs.x + ((lane < 16) ? other : -other) * cs.y;
  }
  if (slot < 16) xr *= q_gain[slot] * 0.125f;   // fold 1/sqrt(D) into q
  dst[lane] = f2bf(xr);
}

// ---------------- MFMA causal flash attention, S^T orientation ---------------
// S^T = mfma(K_frag, Q_frag): one softmax row per lane (quad-replicated).
// P exits in C-layout with 4 consecutive keys per reg group -> b64 stores.
// PV as O^T = mfma(V^T_frag, P_frag). Static max 12 (|q'|<=1.5, |k|=8).
__global__ __launch_bounds__(256) void attn_mfma(
    const u16* __restrict__ qh, const u16* __restrict__ kh,
    const u16* __restrict__ vT, const float* __restrict__ qkv,
    u16* __restrict__ yo)
{
  __shared__ u16 ks[64][64];     // [key][d],   col ^= (key&7)*8
  __shared__ u16 vs[64][64];     // [d][key],   col ^= (d&7)*8   (V^T)
  __shared__ u16 ps[4][16][64];  // [wave][query][key], col ^= (query&7)*8

  const int tid = threadIdx.x;
  const int lane = tid & 63, wq = tid >> 6;
  const int n = lane & 15, quad = lane >> 4;
  const int p = blockIdx.x;                     // pair 0..15
  const int h = blockIdx.y, b = blockIdx.z;
  const int kv = h >> 2;
  const int tiles[2] = {p, 31 - p};             // tile 0 (short), tile 1 (long)
  const u16* kbase = kh + ((size_t)(b * kHKV + kv) * kT) * kD;
  const u16* vbase = vT + ((size_t)(b * kHKV + kv) * kD) * kT;

  short8 qa[2][2];                // Q B-frags (col=query n, k=d contiguous)
  {
    const u16* qb = qh + ((size_t)(b * kH + h) * kT) * kD;
    #pragma unroll
    for (int u = 0; u < 2; ++u) {
      const size_t row = (size_t)(tiles[u] * 64 + wq * 16 + n) * kD;
      qa[u][0] = *(const short8*)(qb + row + quad * 8);
      qa[u][1] = *(const short8*)(qb + row + 32 + quad * 8);
    }
  }

  const int sr = tid >> 3;            // 0..31 (+32 second chunk)
  const int sc = (tid & 7) * 8;
  const int scs = sc ^ ((sr & 7) * 8);

  float l_r[2] = {0.0f, 0.0f};
  float4v acc[2][4];                  // O^T: [u][d-block g][i]: d=g*16+quad*4+i, query=n
  #pragma unroll
  for (int u = 0; u < 2; ++u)
    #pragma unroll
    for (int g = 0; g < 4; ++g) { acc[u][g][0]=0.f; acc[u][g][1]=0.f; acc[u][g][2]=0.f; acc[u][g][3]=0.f; }

  short8 kr0, kr1, vr0, vr1;
  auto loadKV = [&](int kt) {
    kr0 = *(const short8*)(kbase + (size_t)(kt * 64 + sr) * kD + sc);
    kr1 = *(const short8*)(kbase + (size_t)(kt * 64 + sr + 32) * kD + sc);
    vr0 = *(const short8*)(vbase + (size_t)sr * kT + kt * 64 + sc);
    vr1 = *(const short8*)(vbase + (size_t)(sr + 32) * kT + kt * 64 + sc);
  };

  auto process = [&](int u, int kt) {
    float4v s[4];
    #pragma unroll
    for (int g = 0; g < 4; ++g) { s[g][0]=0.f; s[g][1]=0.f; s[g][2]=0.f; s[g][3]=0.f; }
    // S^T[key][query]: A = K rows, B = Q
    #pragma unroll
    for (int g = 0; g < 4; ++g) {
      const short8 kb0 = *(const short8*)&ks[g * 16 + n][(quad * 8) ^ ((n & 7) * 8)];
      s[g] = __builtin_amdgcn_mfma_f32_16x16x32_bf16(kb0, qa[u][0], s[g], 0, 0, 0);
      const short8 kb1 = *(const short8*)&ks[g * 16 + n][(32 + quad * 8) ^ ((n & 7) * 8)];
      s[g] = __builtin_amdgcn_mfma_f32_16x16x32_bf16(kb1, qa[u][1], s[g], 0, 0, 0);
    }
    if (kt == tiles[u]) {   // diagonal: mask key j > query m (local coords)
      const int mloc = wq * 16 + n;
      #pragma unroll
      for (int g = 0; g < 4; ++g)
        #pragma unroll
        for (int i = 0; i < 4; ++i)
          if (g * 16 + quad * 4 + i > mloc) s[g][i] = -__builtin_inff();
    }
    // softmax: this lane owns ONE query row (16 of its 64 keys)
    float pf[4][4]; float rs = 0.0f;
    #pragma unroll
    for (int g = 0; g < 4; ++g)
      #pragma unroll
      for (int i = 0; i < 4; ++i) { pf[g][i] = __expf(s[g][i] - 12.0f); rs += pf[g][i]; }
    rs += __shfl_xor(rs, 16);
    rs += __shfl_xor(rs, 32);
    l_r[u] += rs;
    #pragma unroll
    for (int g = 0; g < 4; ++g) {
      ushort4v pk;
      pk[0] = f2bf(pf[g][0]); pk[1] = f2bf(pf[g][1]);
      pk[2] = f2bf(pf[g][2]); pk[3] = f2bf(pf[g][3]);
      *(ushort4v*)&ps[wq][n][(g * 16 + quad * 4) ^ ((n & 7) * 8)] = pk;   // b64
    }
    // P back as B-frag (row n = query, k = key contiguous); same wave, no barrier
    const short8 pb0 = *(const short8*)&ps[wq][n][(quad * 8) ^ ((n & 7) * 8)];
    const short8 pb1 = *(const short8*)&ps[wq][n][(32 + quad * 8) ^ ((n & 7) * 8)];
    // O^T += V^T * P
    #pragma unroll
    for (int g = 0; g < 4; ++g) {
      const short8 vb0 = *(const short8*)&vs[g * 16 + n][(quad * 8) ^ ((n & 7) * 8)];
      acc[u][g] = __builtin_amdgcn_mfma_f32_16x16x32_bf16(vb0, pb0, acc[u][g], 0, 0, 0);
      const short8 vb1 = *(const short8*)&vs[g * 16 + n][(32 + quad * 8) ^ ((n & 7) * 8)];
      acc[u][g] = __builtin_amdgcn_mfma_f32_16x16x32_bf16(vb1, pb1, acc[u][g], 0, 0, 0);
    }
  };

  const int kmax = tiles[1];
  loadKV(0);
  for (int kt = 0; kt <= kmax; ++kt) {
    __syncthreads();
    *(short8*)&ks[sr][scs]      = kr0;
    *(short8*)&ks[sr + 32][scs] = kr1;
    *(short8*)&vs[sr][scs]      = vr0;
    *(short8*)&vs[sr + 32][scs] = vr1;
    __syncthreads();
    if (kt < kmax) loadKV(kt + 1);
    process(1, kt);                 // long tile, always active
    if (kt <= tiles[0]) process(0, kt);
  }

  // epilogue: y = O/l; remove projection onto normalized v (fp32 from qkv)
  #pragma unroll
  for (int u = 0; u < 2; ++u) {
    const int tok = b * kT + tiles[u] * 64 + wq * 16 + n;
    const float invl = 1.0f / l_r[u];
    float4 vv[4]; float nn = 0.0f, syr = 0.0f;
    #pragma unroll
    for (int g = 0; g < 4; ++g) {
      vv[g] = *(const float4*)(qkv + (size_t)tok * kQKVN + kDim + kHKV * kD + kv * kD + g * 16 + quad * 4);
      nn  += vv[g].x * vv[g].x + vv[g].y * vv[g].y + vv[g].z * vv[g].z + vv[g].w * vv[g].w;
      syr += acc[u][g][0] * vv[g].x + acc[u][g][1] * vv[g].y + acc[u][g][2] * vv[g].z + acc[u][g][3] * vv[g].w;
    }
    nn  += __shfl_xor(nn, 16);  nn  += __shfl_xor(nn, 32);
    syr += __shfl_xor(syr, 16); syr += __shfl_xor(syr, 32);
    const float inv = 1.0f / fmaxf(sqrtf(nn), 1e-12f);
    const float coef = syr * invl * inv * inv;
    #pragma unroll
    for (int g = 0; g < 4; ++g) {
      const float vf[4] = {vv[g].x, vv[g].y, vv[g].z, vv[g].w};
      ushort4v ow;
      #pragma unroll
      for (int i = 0; i < 4; ++i)
        ow[i] = f2bf(acc[u][g][i] * invl - coef * vf[i]);
      *(ushort4v*)(yo + (size_t)tok * kDim + h * kD + g * 16 + quad * 4) = ow;
    }
  }
}

// ------------------------------- launch --------------------------------------
extern "C" void kernel_launch(void* const* d_in, const int* in_sizes, int n_in,
                              void* d_out, int out_size, void* d_ws, size_t ws_size,
                              hipStream_t stream) {
  (void)in_sizes; (void)n_in; (void)out_size; (void)ws_size;
  const float* x      = (const float*)d_in[0];
  const float* w_q    = (const float*)d_in[1];
  const float* w_k    = (const float*)d_in[2];
  const float* w_v    = (const float*)d_in[3];
  const float* w_proj = (const float*)d_in[4];
  const float* q_gain = (const float*)d_in[5];

  char* wsb = (char*)d_ws;
  u16* wqkv = (u16*)wsb;  wsb += (size_t)1536 * 1024 * 2;   // fused QKV weights
  u16* wpq  = (u16*)wsb;  wsb += (size_t)1024 * 1024 * 2;
  u16* xb   = (u16*)wsb;  wsb += (size_t)kTok * kDim * 2;
  float* qkv = (float*)wsb; wsb += (size_t)kTok * kQKVN * 4;
  u16* qh   = (u16*)wsb;  wsb += (size_t)kTok * kDim * 2;
  u16* khb  = (u16*)wsb;  wsb += (size_t)kTok * kHKV * kD * 2;
  u16* vTb  = (u16*)wsb;  wsb += (size_t)kTok * kHKV * kD * 2;
  u16* yo   = (u16*)wsb;  wsb += (size_t)kTok * kDim * 2;
  float2* ropetab = (float2*)wsb; wsb += (size_t)kT * 16 * sizeof(float2);

  // 1) fused prep: rope table + x->bf16 + all weight fake-quant
  prep_kernel<<<4736, 256, 0, stream>>>(x, w_q, w_k, w_v, w_proj,
                                        xb, wqkv, wpq, ropetab);

  // 2) fused QKV GEMM (fp32 out + bf16 V^T side output)
  gemm128<<<dim3(12, 32), 256, 0, stream>>>(xb, wqkv, qkv, kDim, kQKVN, vTb);

  // 3) RMSNorm + RoPE + gain/8 -> bf16 q/k layouts (table-driven)
  normrope_kernel<<<kTok * 20 / 4, 256, 0, stream>>>(qkv, q_gain, ropetab, qh, khb);

  // 4) paired MFMA flash attention + projection removal -> yo (bf16)
  attn_mfma<<<dim3(16, kH, 2), 256, 0, stream>>>(qh, khb, vTb, qkv, yo);

  // 5) output projection (fp32 out)
  gemm128<<<dim3(8, 32), 256, 0, stream>>>(yo, wpq, (float*)d_out, kDim, kDim, nullptr);
}

// Round 7
// 167.439 us; speedup vs baseline: 5.8417x; 1.1834x over previous
//
#include <hip/hip_runtime.h>
#include <math.h>

typedef unsigned short u16;
typedef __attribute__((ext_vector_type(8))) short short8;
typedef __attribute__((ext_vector_type(4))) float float4v;
typedef __attribute__((ext_vector_type(4))) u16 ushort4v;

namespace {
constexpr int kT    = 2048;
constexpr int kDim  = 1024;
constexpr int kH    = 16;
constexpr int kHKV  = 4;
constexpr int kD    = 64;
constexpr int kTok  = 4096;   // B*T
constexpr int kQKVN = 1536;   // DIM + 2*HKV*D
}

__device__ __forceinline__ u16 f2bf(float f) {
  unsigned int u = __builtin_bit_cast(unsigned int, f);
  u = (u + 0x7FFFu + ((u >> 16) & 1u)) >> 16;   // RNE
  return (u16)u;
}

// ---------------- fused prep: rope table + x->bf16 + 4x fake-quant -----------
// blocks [0,128): rope table; [128,2176): cvt x; [2176,4736): quant rows.
__global__ __launch_bounds__(256) void prep_kernel(
    const float* __restrict__ x,
    const float* __restrict__ w_q, const float* __restrict__ w_k,
    const float* __restrict__ w_v, const float* __restrict__ w_proj,
    u16* __restrict__ xb, u16* __restrict__ wqkv, u16* __restrict__ wpq,
    float2* __restrict__ ropetab)
{
  __shared__ float red[4];
  const int bid = blockIdx.x, tid = threadIdx.x;

  if (bid < 128) {                       // rope table (bitwise-same transcendentals)
    const int idx = bid * 256 + tid;     // 0..32767
    const int t = idx >> 4, i = idx & 15;
    const float fr = (float)t * powf(10000.0f, -(float)i * (1.0f / 16.0f));
    ropetab[idx] = make_float2(cosf(fr), sinf(fr));
    return;
  }
  if (bid < 2176) {                      // x -> bf16, 8 elems/thread
    const size_t i = ((size_t)(bid - 128) * 256 + tid) * 8;
    const float4 a = *(const float4*)(x + i);
    const float4 b = *(const float4*)(x + i + 4);
    short8 r;
    r[0] = (short)f2bf(a.x); r[1] = (short)f2bf(a.y);
    r[2] = (short)f2bf(a.z); r[3] = (short)f2bf(a.w);
    r[4] = (short)f2bf(b.x); r[5] = (short)f2bf(b.y);
    r[6] = (short)f2bf(b.z); r[7] = (short)f2bf(b.w);
    *(short8*)(xb + i) = r;
    return;
  }
  // fake-quant: one block per weight row (1024 cols, 4/thread, register-held)
  const int rid = bid - 2176;            // 0..2559
  const float* src; u16* dst; float halfv;
  if (rid < 1024)      { src = w_q    + (size_t)rid * 1024;          dst = wqkv + (size_t)rid * 1024;          halfv = 32.0f; }
  else if (rid < 1280) { src = w_k    + (size_t)(rid - 1024) * 1024; dst = wqkv + (size_t)rid * 1024;          halfv = 32.0f; }
  else if (rid < 1536) { src = w_v    + (size_t)(rid - 1280) * 1024; dst = wqkv + (size_t)rid * 1024;          halfv = 16.0f; }
  else                 { src = w_proj + (size_t)(rid - 1536) * 1024; dst = wpq  + (size_t)(rid - 1536) * 1024; halfv = 16.0f; }

  const float4 v4 = *(const float4*)(src + tid * 4);
  float mx = fmaxf(fmaxf(fabsf(v4.x), fabsf(v4.y)), fmaxf(fabsf(v4.z), fabsf(v4.w)));
  #pragma unroll
  for (int m = 1; m < 64; m <<= 1) mx = fmaxf(mx, __shfl_xor(mx, m));
  if ((tid & 63) == 0) red[tid >> 6] = mx;
  __syncthreads();
  mx = fmaxf(fmaxf(red[0], red[1]), fmaxf(red[2], red[3]));
  const float wmax = fmaxf(mx, 1e-5f);
  const float inv_half = 1.0f / halfv;
  const float vals[4] = {v4.x, v4.y, v4.z, v4.w};
  ushort4v o;
  #pragma unroll
  for (int j = 0; j < 4; ++j) {
    float r = rintf(vals[j] / wmax * halfv);
    r = fminf(fmaxf(r, -halfv), halfv - 1.0f);
    o[j] = f2bf(r * inv_half * wmax);
  }
  *(ushort4v*)(dst + tid * 4) = o;
}

// ======== 128Mx64N bf16 MFMA GEMM core (4 waves x 32x64, BK=32) ==============
// Each wave: rows wm..wm+31 (mi in {0,1}), all 64 cols (ni 0..3).
// acc[mi][ni][i]: row = by*128 + wv*32 + mi*16 + quad*4 + i, col = ni*16 + n.
#define GEMM_CORE(A_, W_, K_, NCOL0_)                                          \
  __shared__ u16 As[128][32];                                                  \
  __shared__ u16 Bs[64][32];                                                   \
  const int tid = threadIdx.x;                                                 \
  const int lane = tid & 63, wv = tid >> 6;                                    \
  const int n = lane & 15, quad = lane >> 4;                                   \
  const int wm = wv * 32;                                                      \
  const int m0 = blockIdx.y * 128;                                             \
  const int sr = tid >> 2, sc = (tid & 3) * 8;                                 \
  const int scs = sc ^ ((sr & 3) * 8);                                         \
  float4v acc[2][4];                                                           \
  _Pragma("unroll")                                                            \
  for (int mi = 0; mi < 2; ++mi)                                               \
    _Pragma("unroll")                                                          \
    for (int ni = 0; ni < 4; ++ni) {                                           \
      acc[mi][ni][0]=0.f; acc[mi][ni][1]=0.f;                                  \
      acc[mi][ni][2]=0.f; acc[mi][ni][3]=0.f; }                                \
  short8 a0r, a1r, b0r;                                                        \
  a0r = *(const short8*)(A_ + (size_t)(m0 + sr) * K_ + sc);                    \
  a1r = *(const short8*)(A_ + (size_t)(m0 + sr + 64) * K_ + sc);               \
  b0r = *(const short8*)(W_ + (size_t)(NCOL0_ + sr) * K_ + sc);                \
  for (int k0 = 0; k0 < K_; k0 += 32) {                                        \
    __syncthreads();                                                           \
    *(short8*)&As[sr][scs] = a0r;  *(short8*)&As[sr + 64][scs] = a1r;          \
    *(short8*)&Bs[sr][scs] = b0r;                                              \
    __syncthreads();                                                           \
    if (k0 + 32 < K_) {                                                        \
      a0r = *(const short8*)(A_ + (size_t)(m0 + sr) * K_ + k0 + 32 + sc);      \
      a1r = *(const short8*)(A_ + (size_t)(m0 + sr + 64) * K_ + k0 + 32 + sc); \
      b0r = *(const short8*)(W_ + (size_t)(NCOL0_ + sr) * K_ + k0 + 32 + sc);  \
    }                                                                          \
    short8 af[2], bf[4];                                                       \
    _Pragma("unroll")                                                          \
    for (int mi = 0; mi < 2; ++mi)                                             \
      af[mi] = *(const short8*)&As[wm + mi * 16 + n][(quad * 8) ^ ((n & 3) * 8)]; \
    _Pragma("unroll")                                                          \
    for (int ni = 0; ni < 4; ++ni)                                             \
      bf[ni] = *(const short8*)&Bs[ni * 16 + n][(quad * 8) ^ ((n & 3) * 8)];   \
    _Pragma("unroll")                                                          \
    for (int mi = 0; mi < 2; ++mi)                                             \
      _Pragma("unroll")                                                        \
      for (int ni = 0; ni < 4; ++ni)                                           \
        acc[mi][ni] = __builtin_amdgcn_mfma_f32_16x16x32_bf16(af[mi], bf[ni], acc[mi][ni], 0, 0, 0); \
  }

// -------- QKV GEMM with fused RMSNorm+RoPE+gain epilogue ---------------------
// Panel (blockIdx.x, 64 cols): 0..15 q head, 16..19 k head, 20..23 v head.
__global__ __launch_bounds__(256) void gemm_qkv(
    const u16* __restrict__ A, const u16* __restrict__ W,
    const float2* __restrict__ ropetab, const float* __restrict__ q_gain,
    u16* __restrict__ qh, u16* __restrict__ kh,
    u16* __restrict__ vT, float* __restrict__ vcmp)
{
  GEMM_CORE(A, W, kDim, (int)(blockIdx.x * 64))

  const int p = blockIdx.x;
  const int rbase = m0 + wm;                 // + mi*16 + quad*4 + i = token row
  const int bI = rbase >> 11;                // batch (128-row tiles never straddle)

  if (p < 20) {
    // q (head h=p) or k (head p-16): RMSNorm over 64 dims + RoPE + gain
    const float gain = (p < 16) ? q_gain[p] * 0.125f : 1.0f;
    u16* dst = (p < 16) ? qh + ((size_t)(bI * kH + p) * kT) * kD
                        : kh + ((size_t)(bI * kHKV + (p - 16)) * kT) * kD;
    #pragma unroll
    for (int mi = 0; mi < 2; ++mi)
      #pragma unroll
      for (int i = 0; i < 4; ++i) {
        const int row = rbase + mi * 16 + quad * 4 + i;
        const int t = row & (kT - 1);
        float v[4];
        #pragma unroll
        for (int ni = 0; ni < 4; ++ni) v[ni] = acc[mi][ni][i];
        float ss = v[0]*v[0] + v[1]*v[1] + v[2]*v[2] + v[3]*v[3];
        #pragma unroll
        for (int m = 1; m < 16; m <<= 1) ss += __shfl_xor(ss, m);
        const float rr = 1.0f / sqrtf(ss * (1.0f / 64.0f) + 1.1920929e-7f);
        #pragma unroll
        for (int ni = 0; ni < 4; ++ni) v[ni] *= rr;
        const float2 cs = ropetab[t * 16 + n];
        const float r0 =  v[0] * cs.x + v[1] * cs.y;
        const float r1 = -v[0] * cs.y + v[1] * cs.x;
        v[0] = r0; v[1] = r1;
        #pragma unroll
        for (int ni = 0; ni < 4; ++ni)
          dst[(size_t)t * kD + ni * 16 + n] = f2bf(v[ni] * gain);
      }
  } else {
    // v head kvh = p-20: bf16 V^T [b][kv][d][T] + compact fp32 v [tok][kv*64+d]
    const int kvh = p - 20;
    u16* vTb = vT + ((size_t)(bI * kHKV + kvh) * kD) * kT;
    #pragma unroll
    for (int mi = 0; mi < 2; ++mi) {
      const int t0 = (rbase + mi * 16 + quad * 4) & (kT - 1);
      #pragma unroll
      for (int ni = 0; ni < 4; ++ni) {
        const int d = ni * 16 + n;
        ushort4v pk;
        pk[0] = f2bf(acc[mi][ni][0]); pk[1] = f2bf(acc[mi][ni][1]);
        pk[2] = f2bf(acc[mi][ni][2]); pk[3] = f2bf(acc[mi][ni][3]);
        *(ushort4v*)(vTb + (size_t)d * kT + t0) = pk;
        #pragma unroll
        for (int i = 0; i < 4; ++i)
          vcmp[(size_t)(rbase + mi * 16 + quad * 4 + i) * (kHKV * kD) + kvh * kD + d] = acc[mi][ni][i];
      }
    }
  }
}

// -------- output projection GEMM (fp32 C) ------------------------------------
__global__ __launch_bounds__(256) void gemm_out(
    const u16* __restrict__ A, const u16* __restrict__ W,
    float* __restrict__ C)
{
  GEMM_CORE(A, W, kDim, (int)(blockIdx.x * 64))
  const int n0 = blockIdx.x * 64;
  #pragma unroll
  for (int mi = 0; mi < 2; ++mi)
    #pragma unroll
    for (int ni = 0; ni < 4; ++ni)
      #pragma unroll
      for (int i = 0; i < 4; ++i)
        C[(size_t)(m0 + wm + mi * 16 + quad * 4 + i) * kDim + n0 + ni * 16 + n] = acc[mi][ni][i];
}

// ---------------- MFMA causal flash attention, S^T orientation ---------------
// S^T = mfma(K_frag, Q_frag): one softmax row per lane (quad-replicated).
// PV as O^T = mfma(V^T_frag, P_frag). Static max 12 (|q'|<=1.5, |k|=8).
__global__ __launch_bounds__(256) void attn_mfma(
    const u16* __restrict__ qh, const u16* __restrict__ kh,
    const u16* __restrict__ vT, const float* __restrict__ vcmp,
    u16* __restrict__ yo)
{
  __shared__ u16 ks[64][64];     // [key][d],   col ^= (key&7)*8
  __shared__ u16 vs[64][64];     // [d][key],   col ^= (d&7)*8   (V^T)
  __shared__ u16 ps[4][16][64];  // [wave][query][key], col ^= (query&7)*8

  const int tid = threadIdx.x;
  const int lane = tid & 63, wq = tid >> 6;
  const int n = lane & 15, quad = lane >> 4;
  const int p = blockIdx.x;                     // pair 0..15
  const int h = blockIdx.y, b = blockIdx.z;
  const int kv = h >> 2;
  const int tiles[2] = {p, 31 - p};             // tile 0 (short), tile 1 (long)
  const u16* kbase = kh + ((size_t)(b * kHKV + kv) * kT) * kD;
  const u16* vbase = vT + ((size_t)(b * kHKV + kv) * kD) * kT;

  short8 qa[2][2];                // Q B-frags (col=query n, k=d contiguous)
  {
    const u16* qb = qh + ((size_t)(b * kH + h) * kT) * kD;
    #pragma unroll
    for (int u = 0; u < 2; ++u) {
      const size_t row = (size_t)(tiles[u] * 64 + wq * 16 + n) * kD;
      qa[u][0] = *(const short8*)(qb + row + quad * 8);
      qa[u][1] = *(const short8*)(qb + row + 32 + quad * 8);
    }
  }

  const int sr = tid >> 3;            // 0..31 (+32 second chunk)
  const int sc = (tid & 7) * 8;
  const int scs = sc ^ ((sr & 7) * 8);

  float l_r[2] = {0.0f, 0.0f};
  float4v acc[2][4];                  // O^T: [u][d-block g][i]: d=g*16+quad*4+i, query=n
  #pragma unroll
  for (int u = 0; u < 2; ++u)
    #pragma unroll
    for (int g = 0; g < 4; ++g) { acc[u][g][0]=0.f; acc[u][g][1]=0.f; acc[u][g][2]=0.f; acc[u][g][3]=0.f; }

  short8 kr0, kr1, vr0, vr1;
  auto loadKV = [&](int kt) {
    kr0 = *(const short8*)(kbase + (size_t)(kt * 64 + sr) * kD + sc);
    kr1 = *(const short8*)(kbase + (size_t)(kt * 64 + sr + 32) * kD + sc);
    vr0 = *(const short8*)(vbase + (size_t)sr * kT + kt * 64 + sc);
    vr1 = *(const short8*)(vbase + (size_t)(sr + 32) * kT + kt * 64 + sc);
  };

  auto process = [&](int u, int kt) {
    float4v s[4];
    #pragma unroll
    for (int g = 0; g < 4; ++g) { s[g][0]=0.f; s[g][1]=0.f; s[g][2]=0.f; s[g][3]=0.f; }
    // S^T[key][query]: A = K rows, B = Q
    #pragma unroll
    for (int g = 0; g < 4; ++g) {
      const short8 kb0 = *(const short8*)&ks[g * 16 + n][(quad * 8) ^ ((n & 7) * 8)];
      s[g] = __builtin_amdgcn_mfma_f32_16x16x32_bf16(kb0, qa[u][0], s[g], 0, 0, 0);
      const short8 kb1 = *(const short8*)&ks[g * 16 + n][(32 + quad * 8) ^ ((n & 7) * 8)];
      s[g] = __builtin_amdgcn_mfma_f32_16x16x32_bf16(kb1, qa[u][1], s[g], 0, 0, 0);
    }
    if (kt == tiles[u]) {   // diagonal: mask key j > query m (local coords)
      const int mloc = wq * 16 + n;
      #pragma unroll
      for (int g = 0; g < 4; ++g)
        #pragma unroll
        for (int i = 0; i < 4; ++i)
          if (g * 16 + quad * 4 + i > mloc) s[g][i] = -__builtin_inff();
    }
    // softmax: this lane owns ONE query row (16 of its 64 keys)
    float pf[4][4]; float rs = 0.0f;
    #pragma unroll
    for (int g = 0; g < 4; ++g)
      #pragma unroll
      for (int i = 0; i < 4; ++i) { pf[g][i] = __expf(s[g][i] - 12.0f); rs += pf[g][i]; }
    rs += __shfl_xor(rs, 16);
    rs += __shfl_xor(rs, 32);
    l_r[u] += rs;
    #pragma unroll
    for (int g = 0; g < 4; ++g) {
      ushort4v pk;
      pk[0] = f2bf(pf[g][0]); pk[1] = f2bf(pf[g][1]);
      pk[2] = f2bf(pf[g][2]); pk[3] = f2bf(pf[g][3]);
      *(ushort4v*)&ps[wq][n][(g * 16 + quad * 4) ^ ((n & 7) * 8)] = pk;   // b64
    }
    // P back as B-frag (row n = query, k = key contiguous); same wave, no barrier
    const short8 pb0 = *(const short8*)&ps[wq][n][(quad * 8) ^ ((n & 7) * 8)];
    const short8 pb1 = *(const short8*)&ps[wq][n][(32 + quad * 8) ^ ((n & 7) * 8)];
    // O^T += V^T * P
    #pragma unroll
    for (int g = 0; g < 4; ++g) {
      const short8 vb0 = *(const short8*)&vs[g * 16 + n][(quad * 8) ^ ((n & 7) * 8)];
      acc[u][g] = __builtin_amdgcn_mfma_f32_16x16x32_bf16(vb0, pb0, acc[u][g], 0, 0, 0);
      const short8 vb1 = *(const short8*)&vs[g * 16 + n][(32 + quad * 8) ^ ((n & 7) * 8)];
      acc[u][g] = __builtin_amdgcn_mfma_f32_16x16x32_bf16(vb1, pb1, acc[u][g], 0, 0, 0);
    }
  };

  const int kmax = tiles[1];
  loadKV(0);
  for (int kt = 0; kt <= kmax; ++kt) {
    __syncthreads();
    *(short8*)&ks[sr][scs]      = kr0;
    *(short8*)&ks[sr + 32][scs] = kr1;
    *(short8*)&vs[sr][scs]      = vr0;
    *(short8*)&vs[sr + 32][scs] = vr1;
    __syncthreads();
    if (kt < kmax) loadKV(kt + 1);
    process(1, kt);                 // long tile, always active
    if (kt <= tiles[0]) process(0, kt);
  }

  // epilogue: y = O/l; remove projection onto normalized v (fp32 from vcmp)
  #pragma unroll
  for (int u = 0; u < 2; ++u) {
    const int tok = b * kT + tiles[u] * 64 + wq * 16 + n;
    const float invl = 1.0f / l_r[u];
    float4 vv[4]; float nn = 0.0f, syr = 0.0f;
    #pragma unroll
    for (int g = 0; g < 4; ++g) {
      vv[g] = *(const float4*)(vcmp + (size_t)tok * (kHKV * kD) + kv * kD + g * 16 + quad * 4);
      nn  += vv[g].x * vv[g].x + vv[g].y * vv[g].y + vv[g].z * vv[g].z + vv[g].w * vv[g].w;
      syr += acc[u][g][0] * vv[g].x + acc[u][g][1] * vv[g].y + acc[u][g][2] * vv[g].z + acc[u][g][3] * vv[g].w;
    }
    nn  += __shfl_xor(nn, 16);  nn  += __shfl_xor(nn, 32);
    syr += __shfl_xor(syr, 16); syr += __shfl_xor(syr, 32);
    const float inv = 1.0f / fmaxf(sqrtf(nn), 1e-12f);
    const float coef = syr * invl * inv * inv;
    #pragma unroll
    for (int g = 0; g < 4; ++g) {
      const float vf[4] = {vv[g].x, vv[g].y, vv[g].z, vv[g].w};
      ushort4v ow;
      #pragma unroll
      for (int i = 0; i < 4; ++i)
        ow[i] = f2bf(acc[u][g][i] * invl - coef * vf[i]);
      *(ushort4v*)(yo + (size_t)tok * kDim + h * kD + g * 16 + quad * 4) = ow;
    }
  }
}

// ------------------------------- launch --------------------------------------
extern "C" void kernel_launch(void* const* d_in, const int* in_sizes, int n_in,
                              void* d_out, int out_size, void* d_ws, size_t ws_size,
                              hipStream_t stream) {
  (void)in_sizes; (void)n_in; (void)out_size; (void)ws_size;
  const float* x      = (const float*)d_in[0];
  const float* w_q    = (const float*)d_in[1];
  const float* w_k    = (const float*)d_in[2];
  const float* w_v    = (const float*)d_in[3];
  const float* w_proj = (const float*)d_in[4];
  const float* q_gain = (const float*)d_in[5];

  char* wsb = (char*)d_ws;
  u16* wqkv = (u16*)wsb;  wsb += (size_t)1536 * 1024 * 2;   // fused QKV weights
  u16* wpq  = (u16*)wsb;  wsb += (size_t)1024 * 1024 * 2;
  u16* xb   = (u16*)wsb;  wsb += (size_t)kTok * kDim * 2;
  u16* qh   = (u16*)wsb;  wsb += (size_t)kTok * kDim * 2;
  u16* khb  = (u16*)wsb;  wsb += (size_t)kTok * kHKV * kD * 2;
  u16* vTb  = (u16*)wsb;  wsb += (size_t)kTok * kHKV * kD * 2;
  u16* yo   = (u16*)wsb;  wsb += (size_t)kTok * kDim * 2;
  float* vcmp = (float*)wsb; wsb += (size_t)kTok * kHKV * kD * 4;
  float2* ropetab = (float2*)wsb; wsb += (size_t)kT * 16 * sizeof(float2);

  // 1) fused prep: rope table + x->bf16 + all weight fake-quant
  prep_kernel<<<4736, 256, 0, stream>>>(x, w_q, w_k, w_v, w_proj,
                                        xb, wqkv, wpq, ropetab);

  // 2) QKV GEMM with fused RMSNorm+RoPE+gain epilogue -> qh/kh/vT/vcmp
  gemm_qkv<<<dim3(24, 32), 256, 0, stream>>>(xb, wqkv, ropetab, q_gain,
                                             qh, khb, vTb, vcmp);

  // 3) paired MFMA flash attention + projection removal -> yo (bf16)
  attn_mfma<<<dim3(16, kH, 2), 256, 0, stream>>>(qh, khb, vTb, vcmp, yo);

  // 4) output projection (fp32 out)
  gemm_out<<<dim3(16, 32), 256, 0, stream>>>(yo, wpq, (float*)d_out);
}